// Round 16
// baseline (285.415 us; speedup 1.0000x reference)
//
#include <hip/hip_runtime.h>
#include <hip/hip_bf16.h>

typedef __attribute__((ext_vector_type(8))) short short8;
typedef __attribute__((ext_vector_type(4))) float f32x4;
typedef __attribute__((ext_vector_type(4))) float fl4;

#define DEVI static __device__ __forceinline__

DEVI short f2bs(float f) { __hip_bfloat16 h = __float2bfloat16(f); short s; __builtin_memcpy(&s, &h, 2); return s; }
DEVI float bs2f(short s) { __hip_bfloat16 h; __builtin_memcpy(&h, &s, 2); return __bfloat162float(h); }
DEVI short8 ld8(const short* p) { return *reinterpret_cast<const short8*>(p); }
DEVI void st8(short* p, short8 v) { *reinterpret_cast<short8*>(p) = v; }
DEVI f32x4 MF(short8 a, short8 b, f32x4 c) { return __builtin_amdgcn_mfma_f32_16x16x32_bf16(a, b, c, 0, 0, 0); }
DEVI void glds16(const short* g, short* l) {
  __builtin_amdgcn_global_load_lds((const __attribute__((address_space(1))) void*)g,
                                   (__attribute__((address_space(3))) void*)l, 16, 0, 0);
}
// T4 single-barrier wait: complete own oldest 6 glds (current tile), publish via s_barrier
DEVI void wait_bar(int last) {
  if (last) asm volatile("s_waitcnt vmcnt(0)" ::: "memory");
  else      asm volatile("s_waitcnt vmcnt(6)" ::: "memory");
  __builtin_amdgcn_s_barrier();
  __builtin_amdgcn_sched_barrier(0);
}
// T1: bijective XCD swizzle (m204)
DEVI int xcd_swz(int bid, int nwg) {
  int q = nwg >> 3, r = nwg & 7;
  int x = bid & 7, i = bid >> 3;
  int base = (x < r) ? x*(q+1) : r*(q+1) + (x - r)*q;
  return base + i;
}

// ---------------- workspace layout (bf16 element offsets) ----------------
constexpr size_t OF_U1CB = 0;              // [512][256][64]
constexpr size_t OF_ZENC = 8388608;        // [64][256][128]
constexpr size_t OF_MATS = 10485760;       // 22 x [512][512]
constexpr size_t OF_FWST = 16252928;       // [16][512][64]
constexpr size_t OF_FT   = 16777216;       // [4][64][512]
constexpr size_t OF_RWST = 16908288;       // [16][512][128]
constexpr size_t OF_RT   = 17956864;       // [8][128][512]
constexpr size_t OF_CB   = 18481152;       // 9 x [16][512]
constexpr size_t OF_WDECB= 18554880;       // [512][576]
constexpr size_t OF_WYB  = 18849792;       // [64][576]
constexpr size_t OF_WX2X = 18886656;       // [512][512]
constexpr size_t OF_D8   = 19148800;       // [70][256][512]
constexpr size_t OF_S8   = 28323840;       // [64][256][512]
constexpr size_t OF_XFIN = 36712448;       // [256][512]
constexpr size_t OF_X0HAT= 36843520;       // [256][512] (unused; x0hat -> S8[0])
constexpr size_t OF_WAUG = 36974592;       // [768][768]
constexpr size_t OF_BIAS = 37564416;       // [16][768]
constexpr size_t OF_CB3  = 37576704;       // [16][512]

enum {
  SL_AD1W=0, SL_AD1T, SL_AD2W, SL_AD2T, SL_AD4W, SL_AD4T, SL_AD8W, SL_AD8T, SL_AD16W, SL_AD16T,
  SL_AE1W, SL_AE1T, SL_AE2W, SL_AE2T, SL_AE4W, SL_AE4T, SL_AE8W, SL_AE8T, SL_AE16W, SL_AE16T,
  SL_QD2W, SL_QE2W
};

// ---------------- prep (vectorized, 8 elems/thread) ----------------
DEVI short8 cvt8(const float* p) {
  fl4 a = *(const fl4*)p, b = *(const fl4*)(p + 4);
  short8 v;
  v[0]=f2bs(a[0]); v[1]=f2bs(a[1]); v[2]=f2bs(a[2]); v[3]=f2bs(a[3]);
  v[4]=f2bs(b[0]); v[5]=f2bs(b[1]); v[6]=f2bs(b[2]); v[7]=f2bs(b[3]);
  return v;
}
DEVI short8 sub8(const float* p, const float* o) {
  fl4 a = *(const fl4*)p, b = *(const fl4*)(p + 4);
  fl4 c = *(const fl4*)o, d = *(const fl4*)(o + 4);
  short8 v;
  v[0]=f2bs(a[0]-c[0]); v[1]=f2bs(a[1]-c[1]); v[2]=f2bs(a[2]-c[2]); v[3]=f2bs(a[3]-c[3]);
  v[4]=f2bs(b[0]-d[0]); v[5]=f2bs(b[1]-d[1]); v[6]=f2bs(b[2]-d[2]); v[7]=f2bs(b[3]-d[7-4]);
  // note: b/d lanes 4..7 map to elements 4..7
  v[7]=f2bs(b[3]-d[3]);
  return v;
}
DEVI short8 gath8(const float* p, int stride) {
  short8 v;
#pragma unroll
  for (int e = 0; e < 8; ++e) v[e] = f2bs(p[(size_t)e*stride]);
  return v;
}

__global__ __launch_bounds__(256) void k_prep(
    const float* __restrict__ Y0, const float* __restrict__ U0, const float* __restrict__ U1,
    const float* __restrict__ Wenc, const float* __restrict__ Wdec,
    const float* __restrict__ Wx2x, const float* __restrict__ Wy,
    const float* __restrict__ bdec, const float* __restrict__ benc,
    short* __restrict__ ws)
{
  const size_t total8 = 12341248 / 8;
  for (size_t gidx = (size_t)blockIdx.x*256 + threadIdx.x; gidx < total8; gidx += (size_t)gridDim.x*256) {
    size_t i = gidx * 8;
    short8 v; size_t dst;
    if (i < 8388608) {
      int r = (int)((i >> 6) & 255), u = (int)(i & 63);
      v = sub8(U1 + i, U0 + (size_t)(511*256 + r)*64 + u);
      dst = OF_U1CB + i;
    } else if ((i -= 8388608) < 2097152) {
      int tt = (int)(i >> 15), r = (int)((i >> 7) & 255), z = (int)(i & 127);
      int t = 448 + tt;
      if (z < 64) v = sub8(Y0 + ((size_t)t*256 + r)*64 + z, Y0 + (size_t)(511*256 + r)*64 + z);
      else        v = sub8(U0 + ((size_t)t*256 + r)*64 + (z-64), U0 + (size_t)(511*256 + r)*64 + (z-64));
      dst = OF_ZENC + i;
    } else if ((i -= 2097152) < 262144) {
      v = cvt8(Wdec + (size_t)(i>>9)*576 + (i&511));
      dst = OF_MATS + (size_t)SL_AD1W*262144 + i;
    } else if ((i -= 262144) < 262144) {
      v = gath8(Wdec + (size_t)(i&511)*576 + (i>>9), 576);
      dst = OF_MATS + (size_t)SL_AD1T*262144 + i;
    } else if ((i -= 262144) < 262144) {
      v = cvt8(Wenc + (size_t)(i>>9)*640 + (i&511));
      dst = OF_MATS + (size_t)SL_AE1W*262144 + i;
    } else if ((i -= 262144) < 262144) {
      v = gath8(Wenc + (size_t)(i&511)*640 + (i>>9), 640);
      dst = OF_MATS + (size_t)SL_AE1T*262144 + i;
    } else if ((i -= 262144) < 294912) {
      v = cvt8(Wdec + i);
      dst = OF_WDECB + i;
    } else if ((i -= 294912) < 36864) {
      v = cvt8(Wy + i);
      dst = OF_WYB + i;
    } else if ((i -= 36864) < 262144) {
      v = cvt8(Wx2x + i);
      dst = OF_WX2X + i;
    } else if ((i -= 262144) < 32768) {
      v = gath8(Wdec + (size_t)(i&511)*576 + 512 + (i>>9), 576);
      dst = OF_FT + i;
    } else if ((i -= 32768) < 32768) {
      v = cvt8(Wdec + (size_t)(i>>6)*576 + 512 + (i&63));
      dst = OF_FWST + (size_t)15*32768 + i;
    } else if ((i -= 32768) < 65536) {
      v = gath8(Wenc + (size_t)(i&511)*640 + 512 + (i>>9), 640);
      dst = OF_RT + i;
    } else if ((i -= 65536) < 65536) {
      v = cvt8(Wenc + (size_t)(i>>7)*640 + 512 + (i&127));
      dst = OF_RWST + (size_t)15*65536 + i;
    } else if ((i -= 65536) < 8192) {
      if (i < 512) v = cvt8(bdec + i); else { for (int e = 0; e < 8; ++e) v[e] = 0; }
      dst = OF_CB + i;                    // CB_B
    } else {
      i -= 8192;
      if (i < 512) v = cvt8(benc + i); else { for (int e = 0; e < 8; ++e) v[e] = 0; }
      dst = OF_CB + 8192 + i;             // CBE_B
    }
    st8(ws + dst, v);
  }
}

// ---------------- batched LDS-tiled GEMM, 64x128, BK=64, 3-buffer single-barrier pipeline ----------------
struct BItem {
  const short* A; const short* Y; short* C; const void* initp;
  float* outF; const float* yOffp;
  int M, N, lda, ldy, ldc, kd64, initMode, tileStart, nN, Tout, ldInit;
};
struct BBatch { BItem it[36]; int n; int tiles; };

__global__ __launch_bounds__(256) void k_bgemm(BBatch b)
{
  __shared__ short As[3*4096];
  __shared__ short Bs[3*8192];
  const int lbid = xcd_swz((int)blockIdx.x, (int)gridDim.x);
  int ii = 0;
  for (int t = 1; t < b.n; ++t) if (lbid >= b.it[t].tileStart) ii = t;
  BItem g = b.it[ii];
  const int tau = lbid - g.tileStart;
  const int R0 = (tau / g.nN) * 64;
  const int C0 = (tau % g.nN) * 128;
  const int tid = threadIdx.x, lane = tid & 63;
  const int l15 = lane & 15;
  const int w = tid >> 6;
  const int srow8 = lane >> 3;
  const int scol8 = ((lane&7) ^ ((lane>>3)&7))*8;
  f32x4 acc[4][2];
  if (g.initMode == 0) {
#pragma unroll
    for (int rt = 0; rt < 4; ++rt)
#pragma unroll
      for (int ct = 0; ct < 2; ++ct)
#pragma unroll
        for (int e = 0; e < 4; ++e) acc[rt][ct][e] = 0.f;
  } else if (g.initMode == 1) {
    const short* C0p = (const short*)g.initp;
#pragma unroll
    for (int rt = 0; rt < 4; ++rt)
#pragma unroll
      for (int ct = 0; ct < 2; ++ct) {
        int c = C0 + w*32 + ct*16 + l15; if (c >= g.N) c = g.N - 1;
#pragma unroll
        for (int e = 0; e < 4; ++e) {
          int r = R0 + rt*16 + 4*(lane>>4) + e; if (r >= g.M) r = g.M - 1;
          acc[rt][ct][e] = bs2f(C0p[(size_t)r*g.ldInit + c]);
        }
      }
  } else {
    const float* v = (const float*)g.initp;
#pragma unroll
    for (int ct = 0; ct < 2; ++ct) {
      int c = C0 + w*32 + ct*16 + l15; if (c >= g.N) c = g.N - 1;
      float vv = v[c];
#pragma unroll
      for (int rt = 0; rt < 4; ++rt)
#pragma unroll
        for (int e = 0; e < 4; ++e) acc[rt][ct][e] = vv;
    }
  }
  auto stage = [&](int kt, int buf) {
    int kb = kt*64;
#pragma unroll
    for (int l = 0; l < 2; ++l) {
      int ra = R0 + w*16 + l*8 + srow8; ra = (ra < g.M) ? ra : g.M - 1;
      glds16(g.A + (size_t)ra*g.lda + kb + scol8, &As[buf*4096 + (w*16 + l*8)*64]);
    }
#pragma unroll
    for (int l = 0; l < 4; ++l) {
      int cb_ = C0 + w*32 + l*8 + srow8; cb_ = (cb_ < g.N) ? cb_ : g.N - 1;
      glds16(g.Y + (size_t)cb_*g.ldy + kb + scol8, &Bs[buf*8192 + (w*32 + l*8)*64]);
    }
  };
  if (g.kd64 > 0) {
    stage(0, 0);
    if (g.kd64 > 1) stage(1, 1);
    for (int kt = 0; kt < g.kd64; ++kt) {
      wait_bar(kt + 1 >= g.kd64);
      if (kt + 2 < g.kd64) stage(kt + 2, (kt + 2) % 3);
      __builtin_amdgcn_sched_barrier(0);
      int cur = kt % 3;
#pragma unroll
      for (int kk2 = 0; kk2 < 2; ++kk2) {
        int pos8 = (((lane>>4) | (kk2<<2)) ^ (lane&7))*8;
        short8 xf[4], yf[2];
#pragma unroll
        for (int rt = 0; rt < 4; ++rt) xf[rt] = ld8(&As[cur*4096 + (rt*16 + l15)*64 + pos8]);
#pragma unroll
        for (int ct = 0; ct < 2; ++ct) yf[ct] = ld8(&Bs[cur*8192 + (w*32 + ct*16 + l15)*64 + pos8]);
#pragma unroll
        for (int ct = 0; ct < 2; ++ct)
#pragma unroll
          for (int rt = 0; rt < 4; ++rt) acc[rt][ct] = MF(xf[rt], yf[ct], acc[rt][ct]);
      }
    }
  }
  if (g.outF) {
#pragma unroll
    for (int rt = 0; rt < 4; ++rt)
#pragma unroll
      for (int ct = 0; ct < 2; ++ct) {
        int c = C0 + w*32 + ct*16 + l15;
        if (c >= g.N) continue;
#pragma unroll
        for (int e = 0; e < 4; ++e) {
          int r = R0 + rt*16 + 4*(lane>>4) + e;
          if (r < g.M)
            g.outF[((size_t)g.Tout*256 + (r & 255))*64 + c] = acc[rt][ct][e] + g.yOffp[(size_t)(r & 255)*64 + c];
        }
      }
  } else {
#pragma unroll
    for (int rt = 0; rt < 4; ++rt)
#pragma unroll
      for (int ct = 0; ct < 2; ++ct) {
        int c = C0 + w*32 + ct*16 + l15;
        if (c >= g.N) continue;
#pragma unroll
        for (int e = 0; e < 4; ++e) {
          int r = R0 + rt*16 + 4*(lane>>4) + e;
          if (r < g.M) g.C[(size_t)r*g.ldc + c] = f2bs(acc[rt][ct][e]);
        }
      }
  }
}

// ---------------- phase 1, 64x128, BK=64, 3-buffer (enc 0..255, dec 256..1279) ----------------
__global__ __launch_bounds__(256) void k_phase1t(
    const short* __restrict__ u1cb, const short* __restrict__ fwst,
    const short* __restrict__ cbD, short* __restrict__ D,
    const short* __restrict__ zenc, const short* __restrict__ rwst,
    const short* __restrict__ cbE, short* __restrict__ Epart)
{
  __shared__ short As[3*4096];
  __shared__ short Bs[3*8192];
  const int lbid = xcd_swz((int)blockIdx.x, (int)gridDim.x);
  const int tid = threadIdx.x, lane = tid & 63;
  const int l15 = lane & 15;
  const int w = tid >> 6;
  const int srow8 = lane >> 3;
  const int scol8 = ((lane&7) ^ ((lane>>3)&7))*8;
  f32x4 acc[4][2];
  if (lbid < 256) {
    const int bb = lbid;
    const int chunk = bb >> 6;             // 0..3
    const int quarter = (bb >> 4) & 3;
    const int R0 = ((bb >> 2) & 3) * 64;
    const int C0 = (bb & 3) * 128;
#pragma unroll
    for (int ct = 0; ct < 2; ++ct) {
      float vv = (quarter == 0) ? bs2f(cbE[C0 + w*32 + ct*16 + l15]) : 0.f;
#pragma unroll
      for (int rt = 0; rt < 4; ++rt)
#pragma unroll
        for (int e = 0; e < 4; ++e) acc[rt][ct][e] = vv;
    }
    auto stage = [&](int kt, int buf) {
      int j = quarter*4 + (kt >> 1), kb = (kt & 1)*64;
#pragma unroll
      for (int l = 0; l < 2; ++l) {
        int ra = R0 + w*16 + l*8 + srow8;
        glds16(zenc + ((size_t)(chunk*16 + j)*256 + ra)*128 + kb + scol8, &As[buf*4096 + (w*16 + l*8)*64]);
      }
#pragma unroll
      for (int l = 0; l < 4; ++l) {
        int cb_ = C0 + w*32 + l*8 + srow8;
        glds16(rwst + ((size_t)j*512 + cb_)*128 + kb + scol8, &Bs[buf*8192 + (w*32 + l*8)*64]);
      }
    };
    stage(0, 0);
    stage(1, 1);
    for (int kt = 0; kt < 8; ++kt) {
      wait_bar(kt + 1 >= 8);
      if (kt + 2 < 8) stage(kt + 2, (kt + 2) % 3);
      __builtin_amdgcn_sched_barrier(0);
      int cur = kt % 3;
#pragma unroll
      for (int kk2 = 0; kk2 < 2; ++kk2) {
        int pos8 = (((lane>>4) | (kk2<<2)) ^ (lane&7))*8;
        short8 xf[4], yf[2];
#pragma unroll
        for (int rt = 0; rt < 4; ++rt) xf[rt] = ld8(&As[cur*4096 + (rt*16 + l15)*64 + pos8]);
#pragma unroll
        for (int ct = 0; ct < 2; ++ct) yf[ct] = ld8(&Bs[cur*8192 + (w*32 + ct*16 + l15)*64 + pos8]);
#pragma unroll
        for (int ct = 0; ct < 2; ++ct)
#pragma unroll
          for (int rt = 0; rt < 4; ++rt) acc[rt][ct] = MF(xf[rt], yf[ct], acc[rt][ct]);
      }
    }
    short* O = Epart + (size_t)(quarter*4 + chunk)*131072;
#pragma unroll
    for (int rt = 0; rt < 4; ++rt)
#pragma unroll
      for (int ct = 0; ct < 2; ++ct) {
        int c = C0 + w*32 + ct*16 + l15;
#pragma unroll
        for (int e = 0; e < 4; ++e) {
          int r = R0 + rt*16 + 4*(lane>>4) + e;
          O[(size_t)r*512 + c] = f2bs(acc[rt][ct][e]);
        }
      }
  } else {
    const int bb = lbid - 256;
    const int chunk = bb >> 4;             // 0..63
    const int R0 = ((bb >> 2) & 3) * 64;
    const int C0 = (bb & 3) * 128;
#pragma unroll
    for (int ct = 0; ct < 2; ++ct) {
      float vv = bs2f(cbD[C0 + w*32 + ct*16 + l15]);
#pragma unroll
      for (int rt = 0; rt < 4; ++rt)
#pragma unroll
        for (int e = 0; e < 4; ++e) acc[rt][ct][e] = vv;
    }
    auto stage = [&](int kt, int buf) {
      int j = kt;
#pragma unroll
      for (int l = 0; l < 2; ++l) {
        int ra = R0 + w*16 + l*8 + srow8;
        glds16(u1cb + ((size_t)(chunk*8 + j)*256 + ra)*64 + scol8, &As[buf*4096 + (w*16 + l*8)*64]);
      }
#pragma unroll
      for (int l = 0; l < 4; ++l) {
        int cb_ = C0 + w*32 + l*8 + srow8;
        glds16(fwst + ((size_t)(8 + j)*512 + cb_)*64 + scol8, &Bs[buf*8192 + (w*32 + l*8)*64]);
      }
    };
    stage(0, 0);
    stage(1, 1);
    for (int kt = 0; kt < 8; ++kt) {
      wait_bar(kt + 1 >= 8);
      if (kt + 2 < 8) stage(kt + 2, (kt + 2) % 3);
      __builtin_amdgcn_sched_barrier(0);
      int cur = kt % 3;
#pragma unroll
      for (int kk2 = 0; kk2 < 2; ++kk2) {
        int pos8 = (((lane>>4) | (kk2<<2)) ^ (lane&7))*8;
        short8 xf[4], yf[2];
#pragma unroll
        for (int rt = 0; rt < 4; ++rt) xf[rt] = ld8(&As[cur*4096 + (rt*16 + l15)*64 + pos8]);
#pragma unroll
        for (int ct = 0; ct < 2; ++ct) yf[ct] = ld8(&Bs[cur*8192 + (w*32 + ct*16 + l15)*64 + pos8]);
#pragma unroll
        for (int ct = 0; ct < 2; ++ct)
#pragma unroll
          for (int rt = 0; rt < 4; ++rt) acc[rt][ct] = MF(xf[rt], yf[ct], acc[rt][ct]);
      }
    }
#pragma unroll
    for (int rt = 0; rt < 4; ++rt)
#pragma unroll
      for (int ct = 0; ct < 2; ++ct) {
        int c = C0 + w*32 + ct*16 + l15;
#pragma unroll
        for (int e = 0; e < 4; ++e) {
          int r = R0 + rt*16 + 4*(lane>>4) + e;
          D[((size_t)chunk*256 + r)*512 + c] = f2bs(acc[rt][ct][e]);
        }
      }
  }
}

// ---------------- add 4 enc partials ----------------
__global__ __launch_bounds__(256) void k_add4(const short* __restrict__ Ep, short* __restrict__ E)
{
  size_t i8 = ((size_t)blockIdx.x*256 + threadIdx.x) * 8;
  int chunk = (int)(i8 >> 17);
  size_t off = i8 & 131071;
  short8 s0 = ld8(Ep + (size_t)(0*4 + chunk)*131072 + off);
  short8 s1 = ld8(Ep + (size_t)(1*4 + chunk)*131072 + off);
  short8 s2 = ld8(Ep + (size_t)(2*4 + chunk)*131072 + off);
  short8 s3 = ld8(Ep + (size_t)(3*4 + chunk)*131072 + off);
  short8 r;
#pragma unroll
  for (int e = 0; e < 8; ++e)
    r[e] = f2bs(bs2f(s0[e]) + bs2f(s1[e]) + bs2f(s2[e]) + bs2f(s3[e]));
  st8(E + (size_t)chunk*131072 + off, r);
}

// ---------------- decode quad-step, BK=64, 3-buffer ----------------
__global__ __launch_bounds__(256) void k_xstep4(
    const short* __restrict__ A, short* __restrict__ C,
    const short* __restrict__ u1cb, const short* __restrict__ W4,
    const short* __restrict__ bias4, const float* __restrict__ yOff,
    float* __restrict__ out, int m4, int yOnly)
{
  __shared__ short As[3*4096];
  __shared__ short Bs[3*8192];
  const int lbid = xcd_swz((int)blockIdx.x, (int)gridDim.x);
  const int tid = threadIdx.x, lane = tid & 63;
  const int l15 = lane & 15;
  const int kq = 8 * (lane >> 4);
  const int w = tid >> 6;
  const int srow8 = lane >> 3;
  const int scol8 = ((lane&7) ^ ((lane>>3)&7))*8;
  int rtile, ctile;
  if (yOnly) { rtile = lbid >> 1; ctile = 4 + (lbid & 1); }
  else { rtile = lbid / 6; ctile = lbid % 6; }
  const int R0 = rtile * 64, C0 = ctile * 128;
  const int chunk = R0 >> 8;
  f32x4 acc[4][2];
#pragma unroll
  for (int ct = 0; ct < 2; ++ct) {
    float bv = bs2f(bias4[C0 + w*32 + ct*16 + l15]);
#pragma unroll
    for (int rt = 0; rt < 4; ++rt)
#pragma unroll
      for (int e = 0; e < 4; ++e) acc[rt][ct][e] = bv;
  }
  auto stage = [&](int kt, int buf) {
    int kb = kt*64;
#pragma unroll
    for (int l = 0; l < 2; ++l) {
      int ra = R0 + w*16 + l*8 + srow8;
      glds16(A + (size_t)ra*512 + kb + scol8, &As[buf*4096 + (w*16 + l*8)*64]);
    }
#pragma unroll
    for (int l = 0; l < 4; ++l) {
      int cb_ = C0 + w*32 + l*8 + srow8;
      glds16(W4 + (size_t)cb_*768 + kb + scol8, &Bs[buf*8192 + (w*32 + l*8)*64]);
    }
  };
  stage(0, 0);
  stage(1, 1);
  for (int kt = 0; kt < 8; ++kt) {
    wait_bar(kt + 1 >= 8);
    if (kt + 2 < 8) stage(kt + 2, (kt + 2) % 3);
    __builtin_amdgcn_sched_barrier(0);
    int cur = kt % 3;
#pragma unroll
    for (int kk2 = 0; kk2 < 2; ++kk2) {
      int pos8 = (((lane>>4) | (kk2<<2)) ^ (lane&7))*8;
      short8 xf[4], yf[2];
#pragma unroll
      for (int rt = 0; rt < 4; ++rt) xf[rt] = ld8(&As[cur*4096 + (rt*16 + l15)*64 + pos8]);
#pragma unroll
      for (int ct = 0; ct < 2; ++ct) yf[ct] = ld8(&Bs[cur*8192 + (w*32 + ct*16 + l15)*64 + pos8]);
#pragma unroll
      for (int ct = 0; ct < 2; ++ct)
#pragma unroll
        for (int rt = 0; rt < 4; ++rt) acc[rt][ct] = MF(xf[rt], yf[ct], acc[rt][ct]);
    }
  }
  // u-tail: K 512..767 = [u_t | u_{t+1} | u_{t+2} | u_{t+3}] (direct from global)
#pragma unroll
  for (int kk2 = 0; kk2 < 8; ++kk2) {
    int dt = kk2 >> 1, uo = (kk2 & 1)*32 + kq;
    short8 uf[4], yf[2];
#pragma unroll
    for (int rt = 0; rt < 4; ++rt) {
      int ur = (chunk*8 + 4*m4 + dt)*256 + ((R0 + rt*16 + l15) & 255);
      uf[rt] = ld8(u1cb + (size_t)ur*64 + uo);
    }
#pragma unroll
    for (int ct = 0; ct < 2; ++ct)
      yf[ct] = ld8(W4 + (size_t)(C0 + w*32 + ct*16 + l15)*768 + 512 + kk2*32 + kq);
#pragma unroll
    for (int ct = 0; ct < 2; ++ct)
#pragma unroll
      for (int rt = 0; rt < 4; ++rt) acc[rt][ct] = MF(uf[rt], yf[ct], acc[rt][ct]);
  }
  if (ctile < 4) {
#pragma unroll
    for (int rt = 0; rt < 4; ++rt)
#pragma unroll
      for (int ct = 0; ct < 2; ++ct) {
        int c = C0 + w*32 + ct*16 + l15;
#pragma unroll
        for (int e = 0; e < 4; ++e) {
          int r = R0 + rt*16 + 4*(lane>>4) + e;
          C[(size_t)r*512 + c] = f2bs(acc[rt][ct][e]);
        }
      }
  } else {
#pragma unroll
    for (int rt = 0; rt < 4; ++rt)
#pragma unroll
      for (int ct = 0; ct < 2; ++ct) {
        int oc = C0 - 512 + w*32 + ct*16 + l15;   // 0..255
        int T = 8*chunk + 4*m4 + 1 + (oc >> 6);
        int col = oc & 63;
#pragma unroll
        for (int e = 0; e < 4; ++e) {
          int rb_ = (R0 + rt*16 + 4*(lane>>4) + e) & 255;
          out[((size_t)T*256 + rb_)*64 + col] = acc[rt][ct][e] + yOff[(size_t)rb_*64 + col];
        }
      }
  }
}

// ---------------- host ----------------
extern "C" void kernel_launch(void* const* d_in, const int* in_sizes, int n_in,
                              void* d_out, int out_size, void* d_ws, size_t ws_size,
                              hipStream_t stream)
{
  const float* Y0   = (const float*)d_in[0];
  const float* U0   = (const float*)d_in[1];
  const float* U1   = (const float*)d_in[2];
  const float* Wenc = (const float*)d_in[3];
  const float* benc = (const float*)d_in[4];
  const float* Wx2x = (const float*)d_in[5];
  const float* bx2x = (const float*)d_in[6];
  const float* Wdec = (const float*)d_in[7];
  const float* bdec = (const float*)d_in[8];
  const float* Wy   = (const float*)d_in[9];
  const float* by   = (const float*)d_in[10];
  float* out = (float*)d_out;
  short* ws = (short*)d_ws;
  const float* yOff = Y0 + (size_t)511*256*64;

  auto MAT = [&](int s) -> short* { return ws + OF_MATS + (size_t)s*262144; };
  auto FTp = [&](int p) -> short* { return ws + OF_FT   + (size_t)p*32768; };
  auto FWs = [&](int j) -> short* { return ws + OF_FWST + (size_t)j*32768; };
  auto RTp = [&](int p) -> short* { return ws + OF_RT   + (size_t)p*65536; };
  auto RWs = [&](int j) -> short* { return ws + OF_RWST + (size_t)j*65536; };
  short* CBB   = ws + OF_CB;
  short* CBEB  = ws + OF_CB + 8192;
  short* CB2   = ws + OF_CB + 2*8192;
  short* CB4   = ws + OF_CB + 3*8192;
  short* CB8   = ws + OF_CB + 4*8192;
  short* CBE2  = ws + OF_CB + 5*8192;
  short* CBE4  = ws + OF_CB + 6*8192;
  short* CBE8  = ws + OF_CB + 7*8192;
  short* CBE16 = ws + OF_CB + 8*8192;
  short* CB3   = ws + OF_CB3;
  short* D8 = ws + OF_D8;
  short* S8 = ws + OF_S8;
  short* WYB = ws + OF_WYB;
  short* W4 = ws + OF_WAUG;
  short* biasb = ws + OF_BIAS;
  short* RX  = W4;
  short* RY1 = W4 + (size_t)512*768;
  short* RY2 = W4 + (size_t)576*768;
  short* RY3 = W4 + (size_t)640*768;
  short* RY4 = W4 + (size_t)704*768;
  auto D8s = [&](int s) -> short* { return D8 + (size_t)s*131072; };
  auto S8s = [&](int s) -> short* { return S8 + (size_t)s*131072; };

  auto addB = [](BBatch& b, const short* A, const short* Y, short* C,
                 int M, int N, int lda, int ldy, int ldc, int im, const void* ip,
                 int ldInit, int kd64) {
    int nN = (N + 127) / 128;
    BItem g{A, Y, C, ip, nullptr, nullptr, M, N, lda, ldy, ldc, kd64, im, b.tiles, nN, 0, ldInit};
    b.it[b.n++] = g; b.tiles += ((M + 63) / 64) * nN;
  };
  auto addSq = [&](BBatch& b, int cs, int xs_, int ys) {
    addB(b, MAT(xs_), MAT(ys), MAT(cs), 512, 512, 512, 512, 512, 0, nullptr, 0, 8);
  };
  auto addFw = [&](BBatch& b, int pq, int wq, int ftp) {
    addB(b, MAT(wq), FTp(ftp), FWs(15 - pq), 512, 64, 512, 512, 64, 0, nullptr, 0, 8);
  };
  auto addFt = [&](BBatch& b, int pdst, int psrc, int wq) {
    addB(b, FTp(psrc), MAT(wq), FTp(pdst), 64, 512, 512, 512, 512, 0, nullptr, 0, 8);
  };
  auto addRw = [&](BBatch& b, int pq, int wq, int rtp) {
    addB(b, MAT(wq), RTp(rtp), RWs(15 - pq), 512, 128, 512, 512, 128, 0, nullptr, 0, 8);
  };
  auto addRt = [&](BBatch& b, int pdst, int psrc, int wq) {
    addB(b, RTp(psrc), MAT(wq), RTp(pdst), 128, 512, 512, 512, 512, 0, nullptr, 0, 8);
  };
  auto addCb = [&](BBatch& b, short* dst, const short* src, int wq) {
    addB(b, src, MAT(wq), dst, 16, 512, 512, 512, 512, 1, src, 512, 8);
  };
  auto addCopy = [&](BBatch& b, const short* src, int ldSrc, short* dst, int M, int N) {
    addB(b, src, src, dst, M, N, ldSrc, ldSrc, 768, 1, src, ldSrc, 0);
  };
  auto addZero = [&](BBatch& b, short* dst, int M, int N) {
    addB(b, WYB, WYB, dst, M, N, 576, 576, 768, 0, nullptr, 0, 0);
  };

  k_prep<<<2048, 256, 0, stream>>>(Y0, U0, U1, Wenc, Wdec, Wx2x, Wy, bdec, benc, ws);

  { BBatch b{}; b.n = 0; b.tiles = 0; // round 1 (q=1)
    addSq(b, SL_AD2W, SL_AD1W, SL_AD1T); addSq(b, SL_AD2T, SL_AD1T, SL_AD1W);
    addSq(b, SL_AE2W, SL_AE1W, SL_AE1T); addSq(b, SL_AE2T, SL_AE1T, SL_AE1W);
    addFw(b, 1, SL_AD1W, 0); addFt(b, 1, 0, SL_AD1W);
    addRw(b, 1, SL_AE1W, 0); addRt(b, 1, 0, SL_AE1W);
    addCb(b, CB2, CBB, SL_AD1W); addCb(b, CBE2, CBEB, SL_AE1W);
    k_bgemm<<<b.tiles, 256, 0, stream>>>(b); }

  { BBatch b{}; b.n = 0; b.tiles = 0; // round 2 (q=2)
    addSq(b, SL_AD4W, SL_AD2W, SL_AD2T); addSq(b, SL_AD4T, SL_AD2T, SL_AD2W);
    addSq(b, SL_AE4W, SL_AE2W, SL_AE2T); addSq(b, SL_AE4T, SL_AE2T, SL_AE2W);
    addFw(b, 2, SL_AD2W, 0); addFw(b, 3, SL_AD2W, 1);
    addFt(b, 2, 0, SL_AD2W); addFt(b, 3, 1, SL_AD2W);
    addRw(b, 2, SL_AE2W, 0); addRw(b, 3, SL_AE2W, 1);
    addRt(b, 2, 0, SL_AE2W); addRt(b, 3, 1, SL_AE2W);
    addCb(b, CB4, CB2, SL_AD2W); addCb(b, CBE4, CBE2, SL_AE2W);
    k_bgemm<<<b.tiles, 256, 0, stream>>>(b); }

  { BBatch b{}; b.n = 0; b.tiles = 0; // round 3 (q=4)
    addSq(b, SL_AD8W, SL_AD4W, SL_AD4T); addSq(b, SL_AD8T, SL_AD4T, SL_AD4W);
    addSq(b, SL_AE8W, SL_AE4W, SL_AE4T); addSq(b, SL_AE8T, SL_AE4T, SL_AE4W);
    for (int p = 0; p < 4; ++p) addFw(b, 4 + p, SL_AD4W, p);
    for (int p = 0; p < 4; ++p) { addRw(b, 4 + p, SL_AE4W, p); addRt(b, 4 + p, p, SL_AE4W); }
    addCb(b, CB8, CB4, SL_AD4W);
    addCb(b, CBE8, CBE4, SL_AE4W);
    k_bgemm<<<b.tiles, 256, 0, stream>>>(b); }

  { BBatch b{}; b.n = 0; b.tiles = 0; // round 4 (q=8)
    addSq(b, SL_AD16W, SL_AD8W, SL_AD8T); addSq(b, SL_AD16T, SL_AD8T, SL_AD8W);
    addSq(b, SL_AE16W, SL_AE8W, SL_AE8T); addSq(b, SL_AE16T, SL_AE8T, SL_AE8W);
    for (int p = 0; p < 8; ++p) addRw(b, 8 + p, SL_AE8W, p);
    addCb(b, CBE16, CBE8, SL_AE8W);
    k_bgemm<<<b.tiles, 256, 0, stream>>>(b); }

  { BBatch b{}; b.n = 0; b.tiles = 0; // round 5: A^32 + asm1
    addSq(b, SL_QD2W, SL_AD16W, SL_AD16T);
    addSq(b, SL_QE2W, SL_AE16W, SL_AE16T);
    addB(b, WYB, MAT(SL_AD1T), RY1, 64, 512, 576, 512, 768, 0, nullptr, 0, 8);        // WyA
    addB(b, WYB, MAT(SL_AD2T), RY2, 64, 512, 576, 512, 768, 0, nullptr, 0, 8);        // WyA2
    addB(b, WYB, FTp(0), RY1 + 512, 64, 64, 576, 512, 768, 1, WYB + 512, 576, 8);     // WyF+Wyu
    addB(b, CBB, MAT(SL_AD2W), CB3, 16, 512, 512, 512, 512, 1, CB2, 512, 8);          // cb3
    addCopy(b, MAT(SL_AD4W), 512, RX, 512, 512);                                      // A4
    addCopy(b, FWs(12), 64, RX + 512, 512, 64);                                       // A3F
    addCopy(b, FWs(13), 64, RX + 576, 512, 64);                                       // A2F
    addCopy(b, FWs(14), 64, RX + 640, 512, 64);                                       // AF
    addCopy(b, FWs(15), 64, RX + 704, 512, 64);                                       // F
    addZero(b, RY1 + 576, 64, 192);
    addZero(b, RY2 + 640, 64, 128);
    addZero(b, RY3 + 704, 64, 64);
    addCopy(b, CB4, 512, biasb, 16, 512);                                             // bias-x = cb4
    addB(b, CBB, WYB, biasb + 512, 16, 64, 512, 576, 768, 2, (const void*)by, 0, 8);  // Wy*cb1+by
    addB(b, CB2, WYB, biasb + 576, 16, 64, 512, 576, 768, 2, (const void*)by, 0, 8);  // Wy*cb2+by
    k_bgemm<<<b.tiles, 256, 0, stream>>>(b); }

  { BBatch b{}; b.n = 0; b.tiles = 0; // asm2
    addB(b, RY2, MAT(SL_AD1T), RY3, 64, 512, 768, 512, 768, 0, nullptr, 0, 8);        // WyA3
    addB(b, RY2, MAT(SL_AD2T), RY4, 64, 512, 768, 512, 768, 0, nullptr, 0, 8);        // WyA4
    addB(b, RY1, FTp(0), RY2 + 512, 64, 64, 768, 512, 768, 0, nullptr, 0, 8);         // WyAF
    addB(b, RY2, FTp(0), RY3 + 512, 64, 64, 768, 512, 768, 0, nullptr, 0, 8);         // WyA2F
    addB(b, CB3, WYB, biasb + 640, 16, 64, 512, 576, 768, 2, (const void*)by, 0, 8);  // Wy*cb3+by
    addB(b, CB4, WYB, biasb + 704, 16, 64, 512, 576, 768, 2, (const void*)by, 0, 8);  // Wy*cb4+by
    k_bgemm<<<b.tiles, 256, 0, stream>>>(b); }

  { BBatch b{}; b.n = 0; b.tiles = 0; // asm3
    addB(b, RY3, FTp(0), RY4 + 512, 64, 64, 768, 512, 768, 0, nullptr, 0, 8);         // WyA3F
    addCopy(b, RY1 + 512, 768, RY2 + 576, 64, 64);                                    // WyF+Wyu
    addCopy(b, RY1 + 512, 768, RY3 + 640, 64, 64);
    addCopy(b, RY1 + 512, 768, RY4 + 704, 64, 64);
    addCopy(b, RY2 + 512, 768, RY3 + 576, 64, 64);                                    // WyAF
    addCopy(b, RY2 + 512, 768, RY4 + 640, 64, 64);
    addCopy(b, RY3 + 512, 768, RY4 + 576, 64, 64);                                    // WyA2F
    k_bgemm<<<b.tiles, 256, 0, stream>>>(b); }

  k_phase1t<<<1280, 256, 0, stream>>>(ws + OF_U1CB, ws + OF_FWST, CB8, D8,
                                      ws + OF_ZENC, ws + OF_RWST, CBE16, S8);

  k_add4<<<256, 256, 0, stream>>>(S8, D8s(64));

  { BBatch b{}; b.n = 0; b.tiles = 0; // pairmerge1: d16_m -> S8[2m+1]; E32_i -> D8[68+i]
    for (int m = 0; m < 32; ++m)
      addB(b, D8s(2*m), MAT(SL_AD8W), S8s(2*m+1), 256, 512, 512, 512, 512, 1, D8s(2*m+1), 512, 8);
    for (int i = 0; i < 2; ++i)
      addB(b, D8s(64+2*i), MAT(SL_AE16W), D8s(68+i), 256, 512, 512, 512, 512, 1, D8s(64+2*i+1), 512, 8);
    k_bgemm<<<b.tiles, 256, 0, stream>>>(b); }

  { BBatch b{}; b.n = 0; b.tiles = 0; // pairmerge2: d32_i -> S8[4i+2]; xfin = E32_0*A32e^T + E32_1
    for (int i = 0; i < 16; ++i)
      addB(b, S8s(4*i+1), MAT(SL_AD16W), S8s(4*i+2), 256, 512, 512, 512, 512, 1, S8s(4*i+3), 512, 8);
    addB(b, D8s(68), MAT(SL_QE2W), ws + OF_XFIN, 256, 512, 512, 512, 512, 1, D8s(69), 512, 8);
    k_bgemm<<<b.tiles, 256, 0, stream>>>(b); }

  { BBatch b{}; b.n = 0; b.tiles = 0; // x0hat -> S8[0]
    addB(b, ws + OF_XFIN, ws + OF_WX2X, S8s(0), 256, 512, 512, 512, 512, 2, (const void*)bx2x, 0, 8);
    k_bgemm<<<b.tiles, 256, 0, stream>>>(b); }

  { BBatch b{}; b.n = 0; b.tiles = 0; // combine: S32_i -> S8[4i]
    addB(b, S8s(0), MAT(SL_QD2W), S8s(4), 256, 512, 512, 512, 512, 1, S8s(2), 512, 8);
    for (int i = 2; i < 16; ++i)
      addB(b, S8s(4*i-6), MAT(SL_QD2W), S8s(4*i), 256, 512, 512, 512, 512, 1, S8s(4*i-2), 512, 8);
    k_bgemm<<<b.tiles, 256, 0, stream>>>(b); }

  { BBatch b{}; b.n = 0; b.tiles = 0; // fill16
    for (int i = 0; i < 16; ++i)
      addB(b, S8s(4*i), MAT(SL_AD16W), S8s(4*i+2), 256, 512, 512, 512, 512, 1, S8s(4*i+1), 512, 8);
    k_bgemm<<<b.tiles, 256, 0, stream>>>(b); }

  { BBatch b{}; b.n = 0; b.tiles = 0; // fill8 + yhat0
    for (int j = 0; j < 32; ++j)
      addB(b, S8s(2*j), MAT(SL_AD8W), S8s(2*j+1), 256, 512, 512, 512, 512, 1, D8s(2*j), 512, 8);
    { BItem g{S8s(0), WYB, nullptr, (const void*)by, out, yOff,
              256, 64, 512, 576, 64, 8, 2, b.tiles, 1, 0, 0};
      b.it[b.n++] = g; b.tiles += 4; }
    k_bgemm<<<b.tiles, 256, 0, stream>>>(b); }

  // ---- decode: 2 quad-step launches ----
  short* Xcur = ws + OF_D8;
  k_xstep4<<<1536, 256, 0, stream>>>(S8, Xcur, ws + OF_U1CB, W4, biasb, yOff, out, 0, 0);
  k_xstep4<<<512, 256, 0, stream>>>(Xcur, nullptr, ws + OF_U1CB, W4, biasb, yOff, out, 1, 1);

  (void)in_sizes; (void)n_in; (void)out_size; (void)ws_size;
}

// Round 17
// 265.879 us; speedup vs baseline: 1.0735x; 1.0735x over previous
//
#include <hip/hip_runtime.h>
#include <hip/hip_bf16.h>

typedef __attribute__((ext_vector_type(8))) short short8;
typedef __attribute__((ext_vector_type(4))) float f32x4;
typedef __attribute__((ext_vector_type(4))) float fl4;

#define DEVI static __device__ __forceinline__

DEVI short f2bs(float f) { __hip_bfloat16 h = __float2bfloat16(f); short s; __builtin_memcpy(&s, &h, 2); return s; }
DEVI float bs2f(short s) { __hip_bfloat16 h; __builtin_memcpy(&h, &s, 2); return __bfloat162float(h); }
DEVI short8 ld8(const short* p) { return *reinterpret_cast<const short8*>(p); }
DEVI void st8(short* p, short8 v) { *reinterpret_cast<short8*>(p) = v; }
DEVI f32x4 MF(short8 a, short8 b, f32x4 c) { return __builtin_amdgcn_mfma_f32_16x16x32_bf16(a, b, c, 0, 0, 0); }
DEVI void glds16(const short* g, short* l) {
  __builtin_amdgcn_global_load_lds((const __attribute__((address_space(1))) void*)g,
                                   (__attribute__((address_space(3))) void*)l, 16, 0, 0);
}
// T4 counted-vmcnt barriers: wait own 6/0 outstanding glds, then publish via raw s_barrier
DEVI void waitN_bar(int last) {
  if (last) asm volatile("s_waitcnt vmcnt(0)" ::: "memory");
  else      asm volatile("s_waitcnt vmcnt(6)" ::: "memory");
  __builtin_amdgcn_s_barrier();
  __builtin_amdgcn_sched_barrier(0);
}
DEVI void end_bar() {
  __builtin_amdgcn_sched_barrier(0);
  __builtin_amdgcn_s_barrier();
}
// T1: bijective XCD swizzle (m204)
DEVI int xcd_swz(int bid, int nwg) {
  int q = nwg >> 3, r = nwg & 7;
  int x = bid & 7, i = bid >> 3;
  int base = (x < r) ? x*(q+1) : r*(q+1) + (x - r)*q;
  return base + i;
}

// ---------------- workspace layout (bf16 element offsets) ----------------
constexpr size_t OF_U1CB = 0;              // [512][256][64]
constexpr size_t OF_ZENC = 8388608;        // [64][256][128]
constexpr size_t OF_MATS = 10485760;       // 22 x [512][512]
constexpr size_t OF_FWST = 16252928;       // [16][512][64]
constexpr size_t OF_FT   = 16777216;       // [4][64][512]
constexpr size_t OF_RWST = 16908288;       // [16][512][128]
constexpr size_t OF_RT   = 17956864;       // [8][128][512]
constexpr size_t OF_CB   = 18481152;       // 9 x [16][512]
constexpr size_t OF_WDECB= 18554880;       // [512][576]
constexpr size_t OF_WYB  = 18849792;       // [64][576]
constexpr size_t OF_WX2X = 18886656;       // [512][512]
constexpr size_t OF_D8   = 19148800;       // [70][256][512]
constexpr size_t OF_S8   = 28323840;       // [64][256][512]
constexpr size_t OF_XFIN = 36712448;       // [256][512]
constexpr size_t OF_X0HAT= 36843520;       // [256][512] (unused; x0hat -> S8[0])
constexpr size_t OF_WAUG = 36974592;       // [768][768]
constexpr size_t OF_BIAS = 37564416;       // [16][768]
constexpr size_t OF_CB3  = 37576704;       // [16][512]

enum {
  SL_AD1W=0, SL_AD1T, SL_AD2W, SL_AD2T, SL_AD4W, SL_AD4T, SL_AD8W, SL_AD8T, SL_AD16W, SL_AD16T,
  SL_AE1W, SL_AE1T, SL_AE2W, SL_AE2T, SL_AE4W, SL_AE4T, SL_AE8W, SL_AE8T, SL_AE16W, SL_AE16T,
  SL_QD2W, SL_QE2W
};

// ---------------- prep (vectorized, 8 elems/thread) ----------------
DEVI short8 cvt8(const float* p) {
  fl4 a = *(const fl4*)p, b = *(const fl4*)(p + 4);
  short8 v;
  v[0]=f2bs(a[0]); v[1]=f2bs(a[1]); v[2]=f2bs(a[2]); v[3]=f2bs(a[3]);
  v[4]=f2bs(b[0]); v[5]=f2bs(b[1]); v[6]=f2bs(b[2]); v[7]=f2bs(b[3]);
  return v;
}
DEVI short8 sub8(const float* p, const float* o) {
  fl4 a = *(const fl4*)p, b = *(const fl4*)(p + 4);
  fl4 c = *(const fl4*)o, d = *(const fl4*)(o + 4);
  short8 v;
  v[0]=f2bs(a[0]-c[0]); v[1]=f2bs(a[1]-c[1]); v[2]=f2bs(a[2]-c[2]); v[3]=f2bs(a[3]-c[3]);
  v[4]=f2bs(b[0]-d[0]); v[5]=f2bs(b[1]-d[1]); v[6]=f2bs(b[2]-d[2]); v[7]=f2bs(b[3]-d[3]);
  return v;
}
DEVI short8 gath8(const float* p, int stride) {
  short8 v;
#pragma unroll
  for (int e = 0; e < 8; ++e) v[e] = f2bs(p[(size_t)e*stride]);
  return v;
}

__global__ __launch_bounds__(256) void k_prep(
    const float* __restrict__ Y0, const float* __restrict__ U0, const float* __restrict__ U1,
    const float* __restrict__ Wenc, const float* __restrict__ Wdec,
    const float* __restrict__ Wx2x, const float* __restrict__ Wy,
    const float* __restrict__ bdec, const float* __restrict__ benc,
    short* __restrict__ ws)
{
  const size_t total8 = 12341248 / 8;
  for (size_t gidx = (size_t)blockIdx.x*256 + threadIdx.x; gidx < total8; gidx += (size_t)gridDim.x*256) {
    size_t i = gidx * 8;
    short8 v; size_t dst;
    if (i < 8388608) {
      int r = (int)((i >> 6) & 255), u = (int)(i & 63);
      v = sub8(U1 + i, U0 + (size_t)(511*256 + r)*64 + u);
      dst = OF_U1CB + i;
    } else if ((i -= 8388608) < 2097152) {
      int tt = (int)(i >> 15), r = (int)((i >> 7) & 255), z = (int)(i & 127);
      int t = 448 + tt;
      if (z < 64) v = sub8(Y0 + ((size_t)t*256 + r)*64 + z, Y0 + (size_t)(511*256 + r)*64 + z);
      else        v = sub8(U0 + ((size_t)t*256 + r)*64 + (z-64), U0 + (size_t)(511*256 + r)*64 + (z-64));
      dst = OF_ZENC + i;
    } else if ((i -= 2097152) < 262144) {
      v = cvt8(Wdec + (size_t)(i>>9)*576 + (i&511));
      dst = OF_MATS + (size_t)SL_AD1W*262144 + i;
    } else if ((i -= 262144) < 262144) {
      v = gath8(Wdec + (size_t)(i&511)*576 + (i>>9), 576);
      dst = OF_MATS + (size_t)SL_AD1T*262144 + i;
    } else if ((i -= 262144) < 262144) {
      v = cvt8(Wenc + (size_t)(i>>9)*640 + (i&511));
      dst = OF_MATS + (size_t)SL_AE1W*262144 + i;
    } else if ((i -= 262144) < 262144) {
      v = gath8(Wenc + (size_t)(i&511)*640 + (i>>9), 640);
      dst = OF_MATS + (size_t)SL_AE1T*262144 + i;
    } else if ((i -= 262144) < 294912) {
      v = cvt8(Wdec + i);
      dst = OF_WDECB + i;
    } else if ((i -= 294912) < 36864) {
      v = cvt8(Wy + i);
      dst = OF_WYB + i;
    } else if ((i -= 36864) < 262144) {
      v = cvt8(Wx2x + i);
      dst = OF_WX2X + i;
    } else if ((i -= 262144) < 32768) {
      v = gath8(Wdec + (size_t)(i&511)*576 + 512 + (i>>9), 576);
      dst = OF_FT + i;
    } else if ((i -= 32768) < 32768) {
      v = cvt8(Wdec + (size_t)(i>>6)*576 + 512 + (i&63));
      dst = OF_FWST + (size_t)15*32768 + i;
    } else if ((i -= 32768) < 65536) {
      v = gath8(Wenc + (size_t)(i&511)*640 + 512 + (i>>9), 640);
      dst = OF_RT + i;
    } else if ((i -= 65536) < 65536) {
      v = cvt8(Wenc + (size_t)(i>>7)*640 + 512 + (i&127));
      dst = OF_RWST + (size_t)15*65536 + i;
    } else if ((i -= 65536) < 8192) {
      if (i < 512) v = cvt8(bdec + i); else { for (int e = 0; e < 8; ++e) v[e] = 0; }
      dst = OF_CB + i;                    // CB_B
    } else {
      i -= 8192;
      if (i < 512) v = cvt8(benc + i); else { for (int e = 0; e < 8; ++e) v[e] = 0; }
      dst = OF_CB + 8192 + i;             // CBE_B
    }
    st8(ws + dst, v);
  }
}

// ---------------- batched LDS-tiled GEMM, 64x128 tiles, BK=64, counted-vmcnt pipeline ----------------
struct BItem {
  const short* A; const short* Y; short* C; const void* initp;
  float* outF; const float* yOffp;
  int M, N, lda, ldy, ldc, kd64, initMode, tileStart, nN, Tout, ldInit;
};
struct BBatch { BItem it[36]; int n; int tiles; };

__global__ __launch_bounds__(256) void k_bgemm(BBatch b)
{
  __shared__ short As[2*4096];
  __shared__ short Bs[2*8192];
  const int lbid = xcd_swz((int)blockIdx.x, (int)gridDim.x);
  int ii = 0;
  for (int t = 1; t < b.n; ++t) if (lbid >= b.it[t].tileStart) ii = t;
  BItem g = b.it[ii];
  const int tau = lbid - g.tileStart;
  const int R0 = (tau / g.nN) * 64;
  const int C0 = (tau % g.nN) * 128;
  const int tid = threadIdx.x, lane = tid & 63;
  const int l15 = lane & 15;
  const int w = tid >> 6;
  const int srow8 = lane >> 3;
  const int scol8 = ((lane&7) ^ ((lane>>3)&7))*8;
  f32x4 acc[4][2];
  if (g.initMode == 0) {
#pragma unroll
    for (int rt = 0; rt < 4; ++rt)
#pragma unroll
      for (int ct = 0; ct < 2; ++ct)
#pragma unroll
        for (int e = 0; e < 4; ++e) acc[rt][ct][e] = 0.f;
  } else if (g.initMode == 1) {
    const short* C0p = (const short*)g.initp;
#pragma unroll
    for (int rt = 0; rt < 4; ++rt)
#pragma unroll
      for (int ct = 0; ct < 2; ++ct) {
        int c = C0 + w*32 + ct*16 + l15; if (c >= g.N) c = g.N - 1;
#pragma unroll
        for (int e = 0; e < 4; ++e) {
          int r = R0 + rt*16 + 4*(lane>>4) + e; if (r >= g.M) r = g.M - 1;
          acc[rt][ct][e] = bs2f(C0p[(size_t)r*g.ldInit + c]);
        }
      }
  } else {
    const float* v = (const float*)g.initp;
#pragma unroll
    for (int ct = 0; ct < 2; ++ct) {
      int c = C0 + w*32 + ct*16 + l15; if (c >= g.N) c = g.N - 1;
      float vv = v[c];
#pragma unroll
      for (int rt = 0; rt < 4; ++rt)
#pragma unroll
        for (int e = 0; e < 4; ++e) acc[rt][ct][e] = vv;
    }
  }
  auto stage = [&](int kt, int buf) {
    int kb = kt*64;
#pragma unroll
    for (int l = 0; l < 2; ++l) {
      int ra = R0 + w*16 + l*8 + srow8; ra = (ra < g.M) ? ra : g.M - 1;
      glds16(g.A + (size_t)ra*g.lda + kb + scol8, &As[buf*4096 + (w*16 + l*8)*64]);
    }
#pragma unroll
    for (int l = 0; l < 4; ++l) {
      int cb_ = C0 + w*32 + l*8 + srow8; cb_ = (cb_ < g.N) ? cb_ : g.N - 1;
      glds16(g.Y + (size_t)cb_*g.ldy + kb + scol8, &Bs[buf*8192 + (w*32 + l*8)*64]);
    }
  };
  if (g.kd64 > 0) {
    stage(0, 0);
    if (g.kd64 > 1) stage(1, 1);
    int cur = 0;
    for (int kt = 0; kt < g.kd64; ++kt) {
      waitN_bar(kt + 1 >= g.kd64);
#pragma unroll
      for (int kk2 = 0; kk2 < 2; ++kk2) {
        int pos8 = (((lane>>4) | (kk2<<2)) ^ (lane&7))*8;
        short8 xf[4], yf[2];
#pragma unroll
        for (int rt = 0; rt < 4; ++rt) xf[rt] = ld8(&As[cur*4096 + (rt*16 + l15)*64 + pos8]);
#pragma unroll
        for (int ct = 0; ct < 2; ++ct) yf[ct] = ld8(&Bs[cur*8192 + (w*32 + ct*16 + l15)*64 + pos8]);
#pragma unroll
        for (int ct = 0; ct < 2; ++ct)
#pragma unroll
          for (int rt = 0; rt < 4; ++rt) acc[rt][ct] = MF(xf[rt], yf[ct], acc[rt][ct]);
      }
      end_bar();
      if (kt + 2 < g.kd64) stage(kt + 2, cur);
      cur ^= 1;
    }
  }
  if (g.outF) {
#pragma unroll
    for (int rt = 0; rt < 4; ++rt)
#pragma unroll
      for (int ct = 0; ct < 2; ++ct) {
        int c = C0 + w*32 + ct*16 + l15;
        if (c >= g.N) continue;
#pragma unroll
        for (int e = 0; e < 4; ++e) {
          int r = R0 + rt*16 + 4*(lane>>4) + e;
          if (r < g.M)
            g.outF[((size_t)g.Tout*256 + (r & 255))*64 + c] = acc[rt][ct][e] + g.yOffp[(size_t)(r & 255)*64 + c];
        }
      }
  } else {
#pragma unroll
    for (int rt = 0; rt < 4; ++rt)
#pragma unroll
      for (int ct = 0; ct < 2; ++ct) {
        int c = C0 + w*32 + ct*16 + l15;
        if (c >= g.N) continue;
#pragma unroll
        for (int e = 0; e < 4; ++e) {
          int r = R0 + rt*16 + 4*(lane>>4) + e;
          if (r < g.M) g.C[(size_t)r*g.ldc + c] = f2bs(acc[rt][ct][e]);
        }
      }
  }
}

// ---------------- phase 1, 64x128 tiles, BK=64, counted-vmcnt (enc 0..255, dec 256..1279) ----------------
__global__ __launch_bounds__(256) void k_phase1t(
    const short* __restrict__ u1cb, const short* __restrict__ fwst,
    const short* __restrict__ cbD, short* __restrict__ D,
    const short* __restrict__ zenc, const short* __restrict__ rwst,
    const short* __restrict__ cbE, short* __restrict__ Epart)
{
  __shared__ short As[2*4096];
  __shared__ short Bs[2*8192];
  const int lbid = xcd_swz((int)blockIdx.x, (int)gridDim.x);
  const int tid = threadIdx.x, lane = tid & 63;
  const int l15 = lane & 15;
  const int w = tid >> 6;
  const int srow8 = lane >> 3;
  const int scol8 = ((lane&7) ^ ((lane>>3)&7))*8;
  f32x4 acc[4][2];
  if (lbid < 256) {
    const int bb = lbid;
    const int chunk = bb >> 6;             // 0..3
    const int quarter = (bb >> 4) & 3;
    const int R0 = ((bb >> 2) & 3) * 64;
    const int C0 = (bb & 3) * 128;
#pragma unroll
    for (int ct = 0; ct < 2; ++ct) {
      float vv = (quarter == 0) ? bs2f(cbE[C0 + w*32 + ct*16 + l15]) : 0.f;
#pragma unroll
      for (int rt = 0; rt < 4; ++rt)
#pragma unroll
        for (int e = 0; e < 4; ++e) acc[rt][ct][e] = vv;
    }
    auto stage = [&](int kt, int buf) {
      int j = quarter*4 + (kt >> 1), kb = (kt & 1)*64;
#pragma unroll
      for (int l = 0; l < 2; ++l) {
        int ra = R0 + w*16 + l*8 + srow8;
        glds16(zenc + ((size_t)(chunk*16 + j)*256 + ra)*128 + kb + scol8, &As[buf*4096 + (w*16 + l*8)*64]);
      }
#pragma unroll
      for (int l = 0; l < 4; ++l) {
        int cb_ = C0 + w*32 + l*8 + srow8;
        glds16(rwst + ((size_t)j*512 + cb_)*128 + kb + scol8, &Bs[buf*8192 + (w*32 + l*8)*64]);
      }
    };
    stage(0, 0);
    stage(1, 1);
    int cur = 0;
    for (int kt = 0; kt < 8; ++kt) {
      waitN_bar(kt + 1 >= 8);
#pragma unroll
      for (int kk2 = 0; kk2 < 2; ++kk2) {
        int pos8 = (((lane>>4) | (kk2<<2)) ^ (lane&7))*8;
        short8 xf[4], yf[2];
#pragma unroll
        for (int rt = 0; rt < 4; ++rt) xf[rt] = ld8(&As[cur*4096 + (rt*16 + l15)*64 + pos8]);
#pragma unroll
        for (int ct = 0; ct < 2; ++ct) yf[ct] = ld8(&Bs[cur*8192 + (w*32 + ct*16 + l15)*64 + pos8]);
#pragma unroll
        for (int ct = 0; ct < 2; ++ct)
#pragma unroll
          for (int rt = 0; rt < 4; ++rt) acc[rt][ct] = MF(xf[rt], yf[ct], acc[rt][ct]);
      }
      end_bar();
      if (kt + 2 < 8) stage(kt + 2, cur);
      cur ^= 1;
    }
    short* O = Epart + (size_t)(quarter*4 + chunk)*131072;
#pragma unroll
    for (int rt = 0; rt < 4; ++rt)
#pragma unroll
      for (int ct = 0; ct < 2; ++ct) {
        int c = C0 + w*32 + ct*16 + l15;
#pragma unroll
        for (int e = 0; e < 4; ++e) {
          int r = R0 + rt*16 + 4*(lane>>4) + e;
          O[(size_t)r*512 + c] = f2bs(acc[rt][ct][e]);
        }
      }
  } else {
    const int bb = lbid - 256;
    const int chunk = bb >> 4;             // 0..63
    const int R0 = ((bb >> 2) & 3) * 64;
    const int C0 = (bb & 3) * 128;
#pragma unroll
    for (int ct = 0; ct < 2; ++ct) {
      float vv = bs2f(cbD[C0 + w*32 + ct*16 + l15]);
#pragma unroll
      for (int rt = 0; rt < 4; ++rt)
#pragma unroll
        for (int e = 0; e < 4; ++e) acc[rt][ct][e] = vv;
    }
    auto stage = [&](int kt, int buf) {
      int j = kt;
#pragma unroll
      for (int l = 0; l < 2; ++l) {
        int ra = R0 + w*16 + l*8 + srow8;
        glds16(u1cb + ((size_t)(chunk*8 + j)*256 + ra)*64 + scol8, &As[buf*4096 + (w*16 + l*8)*64]);
      }
#pragma unroll
      for (int l = 0; l < 4; ++l) {
        int cb_ = C0 + w*32 + l*8 + srow8;
        glds16(fwst + ((size_t)(8 + j)*512 + cb_)*64 + scol8, &Bs[buf*8192 + (w*32 + l*8)*64]);
      }
    };
    stage(0, 0);
    stage(1, 1);
    int cur = 0;
    for (int kt = 0; kt < 8; ++kt) {
      waitN_bar(kt + 1 >= 8);
#pragma unroll
      for (int kk2 = 0; kk2 < 2; ++kk2) {
        int pos8 = (((lane>>4) | (kk2<<2)) ^ (lane&7))*8;
        short8 xf[4], yf[2];
#pragma unroll
        for (int rt = 0; rt < 4; ++rt) xf[rt] = ld8(&As[cur*4096 + (rt*16 + l15)*64 + pos8]);
#pragma unroll
        for (int ct = 0; ct < 2; ++ct) yf[ct] = ld8(&Bs[cur*8192 + (w*32 + ct*16 + l15)*64 + pos8]);
#pragma unroll
        for (int ct = 0; ct < 2; ++ct)
#pragma unroll
          for (int rt = 0; rt < 4; ++rt) acc[rt][ct] = MF(xf[rt], yf[ct], acc[rt][ct]);
      }
      end_bar();
      if (kt + 2 < 8) stage(kt + 2, cur);
      cur ^= 1;
    }
#pragma unroll
    for (int rt = 0; rt < 4; ++rt)
#pragma unroll
      for (int ct = 0; ct < 2; ++ct) {
        int c = C0 + w*32 + ct*16 + l15;
#pragma unroll
        for (int e = 0; e < 4; ++e) {
          int r = R0 + rt*16 + 4*(lane>>4) + e;
          D[((size_t)chunk*256 + r)*512 + c] = f2bs(acc[rt][ct][e]);
        }
      }
  }
}

// ---------------- add 4 enc partials ----------------
__global__ __launch_bounds__(256) void k_add4(const short* __restrict__ Ep, short* __restrict__ E)
{
  size_t i8 = ((size_t)blockIdx.x*256 + threadIdx.x) * 8;
  int chunk = (int)(i8 >> 17);
  size_t off = i8 & 131071;
  short8 s0 = ld8(Ep + (size_t)(0*4 + chunk)*131072 + off);
  short8 s1 = ld8(Ep + (size_t)(1*4 + chunk)*131072 + off);
  short8 s2 = ld8(Ep + (size_t)(2*4 + chunk)*131072 + off);
  short8 s3 = ld8(Ep + (size_t)(3*4 + chunk)*131072 + off);
  short8 r;
#pragma unroll
  for (int e = 0; e < 8; ++e)
    r[e] = f2bs(bs2f(s0[e]) + bs2f(s1[e]) + bs2f(s2[e]) + bs2f(s3[e]));
  st8(E + (size_t)chunk*131072 + off, r);
}

// ---------------- decode quad-step, BK=64, counted-vmcnt ----------------
__global__ __launch_bounds__(256) void k_xstep4(
    const short* __restrict__ A, short* __restrict__ C,
    const short* __restrict__ u1cb, const short* __restrict__ W4,
    const short* __restrict__ bias4, const float* __restrict__ yOff,
    float* __restrict__ out, int m4, int yOnly)
{
  __shared__ short As[2*4096];
  __shared__ short Bs[2*8192];
  const int lbid = xcd_swz((int)blockIdx.x, (int)gridDim.x);
  const int tid = threadIdx.x, lane = tid & 63;
  const int l15 = lane & 15;
  const int kq = 8 * (lane >> 4);
  const int w = tid >> 6;
  const int srow8 = lane >> 3;
  const int scol8 = ((lane&7) ^ ((lane>>3)&7))*8;
  int rtile, ctile;
  if (yOnly) { rtile = lbid >> 1; ctile = 4 + (lbid & 1); }
  else { rtile = lbid / 6; ctile = lbid % 6; }
  const int R0 = rtile * 64, C0 = ctile * 128;
  const int chunk = R0 >> 8;
  f32x4 acc[4][2];
#pragma unroll
  for (int ct = 0; ct < 2; ++ct) {
    float bv = bs2f(bias4[C0 + w*32 + ct*16 + l15]);
#pragma unroll
    for (int rt = 0; rt < 4; ++rt)
#pragma unroll
      for (int e = 0; e < 4; ++e) acc[rt][ct][e] = bv;
  }
  auto stage = [&](int kt, int buf) {
    int kb = kt*64;
#pragma unroll
    for (int l = 0; l < 2; ++l) {
      int ra = R0 + w*16 + l*8 + srow8;
      glds16(A + (size_t)ra*512 + kb + scol8, &As[buf*4096 + (w*16 + l*8)*64]);
    }
#pragma unroll
    for (int l = 0; l < 4; ++l) {
      int cb_ = C0 + w*32 + l*8 + srow8;
      glds16(W4 + (size_t)cb_*768 + kb + scol8, &Bs[buf*8192 + (w*32 + l*8)*64]);
    }
  };
  stage(0, 0);
  stage(1, 1);
  int cur = 0;
  for (int kt = 0; kt < 8; ++kt) {
    waitN_bar(kt + 1 >= 8);
#pragma unroll
    for (int kk2 = 0; kk2 < 2; ++kk2) {
      int pos8 = (((lane>>4) | (kk2<<2)) ^ (lane&7))*8;
      short8 xf[4], yf[2];
#pragma unroll
      for (int rt = 0; rt < 4; ++rt) xf[rt] = ld8(&As[cur*4096 + (rt*16 + l15)*64 + pos8]);
#pragma unroll
      for (int ct = 0; ct < 2; ++ct) yf[ct] = ld8(&Bs[cur*8192 + (w*32 + ct*16 + l15)*64 + pos8]);
#pragma unroll
      for (int ct = 0; ct < 2; ++ct)
#pragma unroll
        for (int rt = 0; rt < 4; ++rt) acc[rt][ct] = MF(xf[rt], yf[ct], acc[rt][ct]);
    }
    end_bar();
    if (kt + 2 < 8) stage(kt + 2, cur);
    cur ^= 1;
  }
  // u-tail: K 512..767 = [u_t | u_{t+1} | u_{t+2} | u_{t+3}] (direct from global)
#pragma unroll
  for (int kk2 = 0; kk2 < 8; ++kk2) {
    int dt = kk2 >> 1, uo = (kk2 & 1)*32 + kq;
    short8 uf[4], yf[2];
#pragma unroll
    for (int rt = 0; rt < 4; ++rt) {
      int ur = (chunk*8 + 4*m4 + dt)*256 + ((R0 + rt*16 + l15) & 255);
      uf[rt] = ld8(u1cb + (size_t)ur*64 + uo);
    }
#pragma unroll
    for (int ct = 0; ct < 2; ++ct)
      yf[ct] = ld8(W4 + (size_t)(C0 + w*32 + ct*16 + l15)*768 + 512 + kk2*32 + kq);
#pragma unroll
    for (int ct = 0; ct < 2; ++ct)
#pragma unroll
      for (int rt = 0; rt < 4; ++rt) acc[rt][ct] = MF(uf[rt], yf[ct], acc[rt][ct]);
  }
  if (ctile < 4) {
#pragma unroll
    for (int rt = 0; rt < 4; ++rt)
#pragma unroll
      for (int ct = 0; ct < 2; ++ct) {
        int c = C0 + w*32 + ct*16 + l15;
#pragma unroll
        for (int e = 0; e < 4; ++e) {
          int r = R0 + rt*16 + 4*(lane>>4) + e;
          C[(size_t)r*512 + c] = f2bs(acc[rt][ct][e]);
        }
      }
  } else {
#pragma unroll
    for (int rt = 0; rt < 4; ++rt)
#pragma unroll
      for (int ct = 0; ct < 2; ++ct) {
        int oc = C0 - 512 + w*32 + ct*16 + l15;   // 0..255
        int T = 8*chunk + 4*m4 + 1 + (oc >> 6);
        int col = oc & 63;
#pragma unroll
        for (int e = 0; e < 4; ++e) {
          int rb_ = (R0 + rt*16 + 4*(lane>>4) + e) & 255;
          out[((size_t)T*256 + rb_)*64 + col] = acc[rt][ct][e] + yOff[(size_t)rb_*64 + col];
        }
      }
  }
}

// ---------------- host ----------------
extern "C" void kernel_launch(void* const* d_in, const int* in_sizes, int n_in,
                              void* d_out, int out_size, void* d_ws, size_t ws_size,
                              hipStream_t stream)
{
  const float* Y0   = (const float*)d_in[0];
  const float* U0   = (const float*)d_in[1];
  const float* U1   = (const float*)d_in[2];
  const float* Wenc = (const float*)d_in[3];
  const float* benc = (const float*)d_in[4];
  const float* Wx2x = (const float*)d_in[5];
  const float* bx2x = (const float*)d_in[6];
  const float* Wdec = (const float*)d_in[7];
  const float* bdec = (const float*)d_in[8];
  const float* Wy   = (const float*)d_in[9];
  const float* by   = (const float*)d_in[10];
  float* out = (float*)d_out;
  short* ws = (short*)d_ws;
  const float* yOff = Y0 + (size_t)511*256*64;

  auto MAT = [&](int s) -> short* { return ws + OF_MATS + (size_t)s*262144; };
  auto FTp = [&](int p) -> short* { return ws + OF_FT   + (size_t)p*32768; };
  auto FWs = [&](int j) -> short* { return ws + OF_FWST + (size_t)j*32768; };
  auto RTp = [&](int p) -> short* { return ws + OF_RT   + (size_t)p*65536; };
  auto RWs = [&](int j) -> short* { return ws + OF_RWST + (size_t)j*65536; };
  short* CBB   = ws + OF_CB;
  short* CBEB  = ws + OF_CB + 8192;
  short* CB2   = ws + OF_CB + 2*8192;
  short* CB4   = ws + OF_CB + 3*8192;
  short* CB8   = ws + OF_CB + 4*8192;
  short* CBE2  = ws + OF_CB + 5*8192;
  short* CBE4  = ws + OF_CB + 6*8192;
  short* CBE8  = ws + OF_CB + 7*8192;
  short* CBE16 = ws + OF_CB + 8*8192;
  short* CB3   = ws + OF_CB3;
  short* D8 = ws + OF_D8;
  short* S8 = ws + OF_S8;
  short* WYB = ws + OF_WYB;
  short* W4 = ws + OF_WAUG;
  short* biasb = ws + OF_BIAS;
  short* RX  = W4;
  short* RY1 = W4 + (size_t)512*768;
  short* RY2 = W4 + (size_t)576*768;
  short* RY3 = W4 + (size_t)640*768;
  short* RY4 = W4 + (size_t)704*768;
  auto D8s = [&](int s) -> short* { return D8 + (size_t)s*131072; };
  auto S8s = [&](int s) -> short* { return S8 + (size_t)s*131072; };

  auto addB = [](BBatch& b, const short* A, const short* Y, short* C,
                 int M, int N, int lda, int ldy, int ldc, int im, const void* ip,
                 int ldInit, int kd64) {
    int nN = (N + 127) / 128;
    BItem g{A, Y, C, ip, nullptr, nullptr, M, N, lda, ldy, ldc, kd64, im, b.tiles, nN, 0, ldInit};
    b.it[b.n++] = g; b.tiles += ((M + 63) / 64) * nN;
  };
  auto addSq = [&](BBatch& b, int cs, int xs_, int ys) {
    addB(b, MAT(xs_), MAT(ys), MAT(cs), 512, 512, 512, 512, 512, 0, nullptr, 0, 8);
  };
  auto addFw = [&](BBatch& b, int pq, int wq, int ftp) {
    addB(b, MAT(wq), FTp(ftp), FWs(15 - pq), 512, 64, 512, 512, 64, 0, nullptr, 0, 8);
  };
  auto addFt = [&](BBatch& b, int pdst, int psrc, int wq) {
    addB(b, FTp(psrc), MAT(wq), FTp(pdst), 64, 512, 512, 512, 512, 0, nullptr, 0, 8);
  };
  auto addRw = [&](BBatch& b, int pq, int wq, int rtp) {
    addB(b, MAT(wq), RTp(rtp), RWs(15 - pq), 512, 128, 512, 512, 128, 0, nullptr, 0, 8);
  };
  auto addRt = [&](BBatch& b, int pdst, int psrc, int wq) {
    addB(b, RTp(psrc), MAT(wq), RTp(pdst), 128, 512, 512, 512, 512, 0, nullptr, 0, 8);
  };
  auto addCb = [&](BBatch& b, short* dst, const short* src, int wq) {
    addB(b, src, MAT(wq), dst, 16, 512, 512, 512, 512, 1, src, 512, 8);
  };
  auto addCopy = [&](BBatch& b, const short* src, int ldSrc, short* dst, int M, int N) {
    addB(b, src, src, dst, M, N, ldSrc, ldSrc, 768, 1, src, ldSrc, 0);
  };
  auto addZero = [&](BBatch& b, short* dst, int M, int N) {
    addB(b, WYB, WYB, dst, M, N, 576, 576, 768, 0, nullptr, 0, 0);
  };

  k_prep<<<2048, 256, 0, stream>>>(Y0, U0, U1, Wenc, Wdec, Wx2x, Wy, bdec, benc, ws);

  { BBatch b{}; b.n = 0; b.tiles = 0; // round 1 (q=1)
    addSq(b, SL_AD2W, SL_AD1W, SL_AD1T); addSq(b, SL_AD2T, SL_AD1T, SL_AD1W);
    addSq(b, SL_AE2W, SL_AE1W, SL_AE1T); addSq(b, SL_AE2T, SL_AE1T, SL_AE1W);
    addFw(b, 1, SL_AD1W, 0); addFt(b, 1, 0, SL_AD1W);
    addRw(b, 1, SL_AE1W, 0); addRt(b, 1, 0, SL_AE1W);
    addCb(b, CB2, CBB, SL_AD1W); addCb(b, CBE2, CBEB, SL_AE1W);
    k_bgemm<<<b.tiles, 256, 0, stream>>>(b); }

  { BBatch b{}; b.n = 0; b.tiles = 0; // round 2 (q=2)
    addSq(b, SL_AD4W, SL_AD2W, SL_AD2T); addSq(b, SL_AD4T, SL_AD2T, SL_AD2W);
    addSq(b, SL_AE4W, SL_AE2W, SL_AE2T); addSq(b, SL_AE4T, SL_AE2T, SL_AE2W);
    addFw(b, 2, SL_AD2W, 0); addFw(b, 3, SL_AD2W, 1);
    addFt(b, 2, 0, SL_AD2W); addFt(b, 3, 1, SL_AD2W);
    addRw(b, 2, SL_AE2W, 0); addRw(b, 3, SL_AE2W, 1);
    addRt(b, 2, 0, SL_AE2W); addRt(b, 3, 1, SL_AE2W);
    addCb(b, CB4, CB2, SL_AD2W); addCb(b, CBE4, CBE2, SL_AE2W);
    k_bgemm<<<b.tiles, 256, 0, stream>>>(b); }

  { BBatch b{}; b.n = 0; b.tiles = 0; // round 3 (q=4)
    addSq(b, SL_AD8W, SL_AD4W, SL_AD4T); addSq(b, SL_AD8T, SL_AD4T, SL_AD4W);
    addSq(b, SL_AE8W, SL_AE4W, SL_AE4T); addSq(b, SL_AE8T, SL_AE4T, SL_AE4W);
    for (int p = 0; p < 4; ++p) addFw(b, 4 + p, SL_AD4W, p);
    for (int p = 0; p < 4; ++p) { addRw(b, 4 + p, SL_AE4W, p); addRt(b, 4 + p, p, SL_AE4W); }
    addCb(b, CB8, CB4, SL_AD4W);
    addCb(b, CBE8, CBE4, SL_AE4W);
    k_bgemm<<<b.tiles, 256, 0, stream>>>(b); }

  { BBatch b{}; b.n = 0; b.tiles = 0; // round 4 (q=8)
    addSq(b, SL_AD16W, SL_AD8W, SL_AD8T); addSq(b, SL_AD16T, SL_AD8T, SL_AD8W);
    addSq(b, SL_AE16W, SL_AE8W, SL_AE8T); addSq(b, SL_AE16T, SL_AE8T, SL_AE8W);
    for (int p = 0; p < 8; ++p) addRw(b, 8 + p, SL_AE8W, p);
    addCb(b, CBE16, CBE8, SL_AE8W);
    k_bgemm<<<b.tiles, 256, 0, stream>>>(b); }

  { BBatch b{}; b.n = 0; b.tiles = 0; // round 5: A^32 + asm1 (inputs all from rounds <=3 / prep)
    addSq(b, SL_QD2W, SL_AD16W, SL_AD16T);
    addSq(b, SL_QE2W, SL_AE16W, SL_AE16T);
    addB(b, WYB, MAT(SL_AD1T), RY1, 64, 512, 576, 512, 768, 0, nullptr, 0, 8);        // WyA
    addB(b, WYB, MAT(SL_AD2T), RY2, 64, 512, 576, 512, 768, 0, nullptr, 0, 8);        // WyA2
    addB(b, WYB, FTp(0), RY1 + 512, 64, 64, 576, 512, 768, 1, WYB + 512, 576, 8);     // WyF+Wyu
    addB(b, CBB, MAT(SL_AD2W), CB3, 16, 512, 512, 512, 512, 1, CB2, 512, 8);          // cb3
    addCopy(b, MAT(SL_AD4W), 512, RX, 512, 512);                                      // A4
    addCopy(b, FWs(12), 64, RX + 512, 512, 64);                                       // A3F
    addCopy(b, FWs(13), 64, RX + 576, 512, 64);                                       // A2F
    addCopy(b, FWs(14), 64, RX + 640, 512, 64);                                       // AF
    addCopy(b, FWs(15), 64, RX + 704, 512, 64);                                       // F
    addZero(b, RY1 + 576, 64, 192);
    addZero(b, RY2 + 640, 64, 128);
    addZero(b, RY3 + 704, 64, 64);
    addCopy(b, CB4, 512, biasb, 16, 512);                                             // bias-x = cb4
    addB(b, CBB, WYB, biasb + 512, 16, 64, 512, 576, 768, 2, (const void*)by, 0, 8);  // Wy*cb1+by
    addB(b, CB2, WYB, biasb + 576, 16, 64, 512, 576, 768, 2, (const void*)by, 0, 8);  // Wy*cb2+by
    k_bgemm<<<b.tiles, 256, 0, stream>>>(b); }

  { BBatch b{}; b.n = 0; b.tiles = 0; // asm2 (reads RY1/RY2/CB3 from round 5)
    addB(b, RY2, MAT(SL_AD1T), RY3, 64, 512, 768, 512, 768, 0, nullptr, 0, 8);        // WyA3
    addB(b, RY2, MAT(SL_AD2T), RY4, 64, 512, 768, 512, 768, 0, nullptr, 0, 8);        // WyA4
    addB(b, RY1, FTp(0), RY2 + 512, 64, 64, 768, 512, 768, 0, nullptr, 0, 8);         // WyAF
    addB(b, RY2, FTp(0), RY3 + 512, 64, 64, 768, 512, 768, 0, nullptr, 0, 8);         // WyA2F
    addB(b, CB3, WYB, biasb + 640, 16, 64, 512, 576, 768, 2, (const void*)by, 0, 8);  // Wy*cb3+by
    addB(b, CB4, WYB, biasb + 704, 16, 64, 512, 576, 768, 2, (const void*)by, 0, 8);  // Wy*cb4+by
    k_bgemm<<<b.tiles, 256, 0, stream>>>(b); }

  { BBatch b{}; b.n = 0; b.tiles = 0; // asm3 (reads RY3 / RY*+512 from asm2)
    addB(b, RY3, FTp(0), RY4 + 512, 64, 64, 768, 512, 768, 0, nullptr, 0, 8);         // WyA3F
    addCopy(b, RY1 + 512, 768, RY2 + 576, 64, 64);                                    // WyF+Wyu
    addCopy(b, RY1 + 512, 768, RY3 + 640, 64, 64);
    addCopy(b, RY1 + 512, 768, RY4 + 704, 64, 64);
    addCopy(b, RY2 + 512, 768, RY3 + 576, 64, 64);                                    // WyAF
    addCopy(b, RY2 + 512, 768, RY4 + 640, 64, 64);
    addCopy(b, RY3 + 512, 768, RY4 + 576, 64, 64);                                    // WyA2F
    k_bgemm<<<b.tiles, 256, 0, stream>>>(b); }

  k_phase1t<<<1280, 256, 0, stream>>>(ws + OF_U1CB, ws + OF_FWST, CB8, D8,
                                      ws + OF_ZENC, ws + OF_RWST, CBE16, S8);

  k_add4<<<256, 256, 0, stream>>>(S8, D8s(64));

  { BBatch b{}; b.n = 0; b.tiles = 0; // pairmerge1: d16_m -> S8[2m+1]; E32_i -> D8[68+i]
    for (int m = 0; m < 32; ++m)
      addB(b, D8s(2*m), MAT(SL_AD8W), S8s(2*m+1), 256, 512, 512, 512, 512, 1, D8s(2*m+1), 512, 8);
    for (int i = 0; i < 2; ++i)
      addB(b, D8s(64+2*i), MAT(SL_AE16W), D8s(68+i), 256, 512, 512, 512, 512, 1, D8s(64+2*i+1), 512, 8);
    k_bgemm<<<b.tiles, 256, 0, stream>>>(b); }

  { BBatch b{}; b.n = 0; b.tiles = 0; // pairmerge2: d32_i -> S8[4i+2]; xfin = E32_0*A32e^T + E32_1
    for (int i = 0; i < 16; ++i)
      addB(b, S8s(4*i+1), MAT(SL_AD16W), S8s(4*i+2), 256, 512, 512, 512, 512, 1, S8s(4*i+3), 512, 8);
    addB(b, D8s(68), MAT(SL_QE2W), ws + OF_XFIN, 256, 512, 512, 512, 512, 1, D8s(69), 512, 8);
    k_bgemm<<<b.tiles, 256, 0, stream>>>(b); }

  { BBatch b{}; b.n = 0; b.tiles = 0; // x0hat = xfin * Wx2x^T + bx2x  -> S8[0] directly
    addB(b, ws + OF_XFIN, ws + OF_WX2X, S8s(0), 256, 512, 512, 512, 512, 2, (const void*)bx2x, 0, 8);
    k_bgemm<<<b.tiles, 256, 0, stream>>>(b); }

  { BBatch b{}; b.n = 0; b.tiles = 0; // combine: S32_i -> S8[4i]  (S8[0] already = x0hat)
    addB(b, S8s(0), MAT(SL_QD2W), S8s(4), 256, 512, 512, 512, 512, 1, S8s(2), 512, 8);
    for (int i = 2; i < 16; ++i)
      addB(b, S8s(4*i-6), MAT(SL_QD2W), S8s(4*i), 256, 512, 512, 512, 512, 1, S8s(4*i-2), 512, 8);
    k_bgemm<<<b.tiles, 256, 0, stream>>>(b); }

  { BBatch b{}; b.n = 0; b.tiles = 0; // fill16: S8[4i+2] = S8[4i]*A16^T + d16_{2i}
    for (int i = 0; i < 16; ++i)
      addB(b, S8s(4*i), MAT(SL_AD16W), S8s(4*i+2), 256, 512, 512, 512, 512, 1, S8s(4*i+1), 512, 8);
    k_bgemm<<<b.tiles, 256, 0, stream>>>(b); }

  { BBatch b{}; b.n = 0; b.tiles = 0; // fill8: S8[2j+1] = S8[2j]*A8^T + d8_{2j}; plus yhat0 (T=0)
    for (int j = 0; j < 32; ++j)
      addB(b, S8s(2*j), MAT(SL_AD8W), S8s(2*j+1), 256, 512, 512, 512, 512, 1, D8s(2*j), 512, 8);
    { BItem g{S8s(0), WYB, nullptr, (const void*)by, out, yOff,
              256, 64, 512, 576, 64, 8, 2, b.tiles, 1, 0, 0};
      b.it[b.n++] = g; b.tiles += 4; }
    k_bgemm<<<b.tiles, 256, 0, stream>>>(b); }

  // ---- decode: 2 quad-step launches ----
  short* Xcur = ws + OF_D8;   // D8 region dead after fill8
  k_xstep4<<<1536, 256, 0, stream>>>(S8, Xcur, ws + OF_U1CB, W4, biasb, yOff, out, 0, 0);
  k_xstep4<<<512, 256, 0, stream>>>(Xcur, nullptr, ws + OF_U1CB, W4, biasb, yOff, out, 1, 1);

  (void)in_sizes; (void)n_in; (void)out_size; (void)ws_size;
}

// Round 18
// 235.453 us; speedup vs baseline: 1.2122x; 1.1292x over previous
//
#include <hip/hip_runtime.h>
#include <hip/hip_bf16.h>

typedef __attribute__((ext_vector_type(8))) short short8;
typedef __attribute__((ext_vector_type(4))) float f32x4;
typedef __attribute__((ext_vector_type(4))) float fl4;

#define DEVI static __device__ __forceinline__

DEVI short f2bs(float f) { __hip_bfloat16 h = __float2bfloat16(f); short s; __builtin_memcpy(&s, &h, 2); return s; }
DEVI float bs2f(short s) { __hip_bfloat16 h; __builtin_memcpy(&h, &s, 2); return __bfloat162float(h); }
DEVI short8 ld8(const short* p) { return *reinterpret_cast<const short8*>(p); }
DEVI void st8(short* p, short8 v) { *reinterpret_cast<short8*>(p) = v; }
DEVI f32x4 MF(short8 a, short8 b, f32x4 c) { return __builtin_amdgcn_mfma_f32_16x16x32_bf16(a, b, c, 0, 0, 0); }
DEVI void glds16(const short* g, short* l) {
  __builtin_amdgcn_global_load_lds((const __attribute__((address_space(1))) void*)g,
                                   (__attribute__((address_space(3))) void*)l, 16, 0, 0);
}
// T4 counted-vmcnt barriers: wait own 6/0 outstanding glds, then publish via raw s_barrier
DEVI void waitN_bar(int last) {
  if (last) asm volatile("s_waitcnt vmcnt(0)" ::: "memory");
  else      asm volatile("s_waitcnt vmcnt(6)" ::: "memory");
  __builtin_amdgcn_s_barrier();
  __builtin_amdgcn_sched_barrier(0);
}
DEVI void end_bar() {
  __builtin_amdgcn_sched_barrier(0);
  __builtin_amdgcn_s_barrier();
}
// T1: bijective XCD swizzle (m204)
DEVI int xcd_swz(int bid, int nwg) {
  int q = nwg >> 3, r = nwg & 7;
  int x = bid & 7, i = bid >> 3;
  int base = (x < r) ? x*(q+1) : r*(q+1) + (x - r)*q;
  return base + i;
}

// ---------------- workspace layout (bf16 element offsets) ----------------
constexpr size_t OF_U1CB = 0;              // [512][256][64]
constexpr size_t OF_ZENC = 8388608;        // [64][256][128]
constexpr size_t OF_MATS = 10485760;       // 22 x [512][512]
constexpr size_t OF_FWST = 16252928;       // [16][512][64]
constexpr size_t OF_FT   = 16777216;       // [4][64][512]
constexpr size_t OF_RWST = 16908288;       // [16][512][128]
constexpr size_t OF_RT   = 17956864;       // [8][128][512]
constexpr size_t OF_CB   = 18481152;       // 9 x [16][512]
constexpr size_t OF_WDECB= 18554880;       // [512][576]
constexpr size_t OF_WYB  = 18849792;       // [64][576]
constexpr size_t OF_WX2X = 18886656;       // [512][512]
constexpr size_t OF_D8   = 19148800;       // [70][256][512]
constexpr size_t OF_S8   = 28323840;       // [64][256][512]
constexpr size_t OF_XFIN = 36712448;       // [256][512]
constexpr size_t OF_X0HAT= 36843520;       // [256][512] (unused; x0hat -> S8[0])
constexpr size_t OF_WAUG = 36974592;       // [768][768]
constexpr size_t OF_BIAS = 37564416;       // [16][768]
constexpr size_t OF_CB3  = 37576704;       // [16][512]

enum {
  SL_AD1W=0, SL_AD1T, SL_AD2W, SL_AD2T, SL_AD4W, SL_AD4T, SL_AD8W, SL_AD8T, SL_AD16W, SL_AD16T,
  SL_AE1W, SL_AE1T, SL_AE2W, SL_AE2T, SL_AE4W, SL_AE4T, SL_AE8W, SL_AE8T, SL_AE16W, SL_AE16T,
  SL_QD2W, SL_QE2W
};

// ---------------- prep (vectorized, 8 elems/thread) ----------------
DEVI short8 cvt8(const float* p) {
  fl4 a = *(const fl4*)p, b = *(const fl4*)(p + 4);
  short8 v;
  v[0]=f2bs(a[0]); v[1]=f2bs(a[1]); v[2]=f2bs(a[2]); v[3]=f2bs(a[3]);
  v[4]=f2bs(b[0]); v[5]=f2bs(b[1]); v[6]=f2bs(b[2]); v[7]=f2bs(b[3]);
  return v;
}
DEVI short8 sub8(const float* p, const float* o) {
  fl4 a = *(const fl4*)p, b = *(const fl4*)(p + 4);
  fl4 c = *(const fl4*)o, d = *(const fl4*)(o + 4);
  short8 v;
  v[0]=f2bs(a[0]-c[0]); v[1]=f2bs(a[1]-c[1]); v[2]=f2bs(a[2]-c[2]); v[3]=f2bs(a[3]-c[3]);
  v[4]=f2bs(b[0]-d[0]); v[5]=f2bs(b[1]-d[1]); v[6]=f2bs(b[2]-d[2]); v[7]=f2bs(b[3]-d[3]);
  return v;
}
DEVI short8 gath8(const float* p, int stride) {
  short8 v;
#pragma unroll
  for (int e = 0; e < 8; ++e) v[e] = f2bs(p[(size_t)e*stride]);
  return v;
}

__global__ __launch_bounds__(256) void k_prep(
    const float* __restrict__ Y0, const float* __restrict__ U0, const float* __restrict__ U1,
    const float* __restrict__ Wenc, const float* __restrict__ Wdec,
    const float* __restrict__ Wx2x, const float* __restrict__ Wy,
    const float* __restrict__ bdec, const float* __restrict__ benc,
    short* __restrict__ ws)
{
  const size_t total8 = 12341248 / 8;
  for (size_t gidx = (size_t)blockIdx.x*256 + threadIdx.x; gidx < total8; gidx += (size_t)gridDim.x*256) {
    size_t i = gidx * 8;
    short8 v; size_t dst;
    if (i < 8388608) {
      int r = (int)((i >> 6) & 255), u = (int)(i & 63);
      v = sub8(U1 + i, U0 + (size_t)(511*256 + r)*64 + u);
      dst = OF_U1CB + i;
    } else if ((i -= 8388608) < 2097152) {
      int tt = (int)(i >> 15), r = (int)((i >> 7) & 255), z = (int)(i & 127);
      int t = 448 + tt;
      if (z < 64) v = sub8(Y0 + ((size_t)t*256 + r)*64 + z, Y0 + (size_t)(511*256 + r)*64 + z);
      else        v = sub8(U0 + ((size_t)t*256 + r)*64 + (z-64), U0 + (size_t)(511*256 + r)*64 + (z-64));
      dst = OF_ZENC + i;
    } else if ((i -= 2097152) < 262144) {
      v = cvt8(Wdec + (size_t)(i>>9)*576 + (i&511));
      dst = OF_MATS + (size_t)SL_AD1W*262144 + i;
    } else if ((i -= 262144) < 262144) {
      v = gath8(Wdec + (size_t)(i&511)*576 + (i>>9), 576);
      dst = OF_MATS + (size_t)SL_AD1T*262144 + i;
    } else if ((i -= 262144) < 262144) {
      v = cvt8(Wenc + (size_t)(i>>9)*640 + (i&511));
      dst = OF_MATS + (size_t)SL_AE1W*262144 + i;
    } else if ((i -= 262144) < 262144) {
      v = gath8(Wenc + (size_t)(i&511)*640 + (i>>9), 640);
      dst = OF_MATS + (size_t)SL_AE1T*262144 + i;
    } else if ((i -= 262144) < 294912) {
      v = cvt8(Wdec + i);
      dst = OF_WDECB + i;
    } else if ((i -= 294912) < 36864) {
      v = cvt8(Wy + i);
      dst = OF_WYB + i;
    } else if ((i -= 36864) < 262144) {
      v = cvt8(Wx2x + i);
      dst = OF_WX2X + i;
    } else if ((i -= 262144) < 32768) {
      v = gath8(Wdec + (size_t)(i&511)*576 + 512 + (i>>9), 576);
      dst = OF_FT + i;
    } else if ((i -= 32768) < 32768) {
      v = cvt8(Wdec + (size_t)(i>>6)*576 + 512 + (i&63));
      dst = OF_FWST + (size_t)15*32768 + i;
    } else if ((i -= 32768) < 65536) {
      v = gath8(Wenc + (size_t)(i&511)*640 + 512 + (i>>9), 640);
      dst = OF_RT + i;
    } else if ((i -= 65536) < 65536) {
      v = cvt8(Wenc + (size_t)(i>>7)*640 + 512 + (i&127));
      dst = OF_RWST + (size_t)15*65536 + i;
    } else if ((i -= 65536) < 8192) {
      if (i < 512) v = cvt8(bdec + i); else { for (int e = 0; e < 8; ++e) v[e] = 0; }
      dst = OF_CB + i;                    // CB_B
    } else {
      i -= 8192;
      if (i < 512) v = cvt8(benc + i); else { for (int e = 0; e < 8; ++e) v[e] = 0; }
      dst = OF_CB + 8192 + i;             // CBE_B
    }
    st8(ws + dst, v);
  }
}

// ---------------- batched LDS-tiled GEMM, 64x128 tiles, BK=64, counted-vmcnt pipeline ----------------
struct BItem {
  const short* A; const short* Y; short* C; const void* initp;
  float* outF; const float* yOffp;
  int M, N, lda, ldy, ldc, kd64, initMode, tileStart, nN, Tout, ldInit;
};
struct BBatch { BItem it[36]; int n; int tiles; };

__global__ __launch_bounds__(256) void k_bgemm(BBatch b)
{
  __shared__ short As[2*4096];
  __shared__ short Bs[2*8192];
  const int lbid = xcd_swz((int)blockIdx.x, (int)gridDim.x);
  int ii = 0;
  for (int t = 1; t < b.n; ++t) if (lbid >= b.it[t].tileStart) ii = t;
  BItem g = b.it[ii];
  const int tau = lbid - g.tileStart;
  const int R0 = (tau / g.nN) * 64;
  const int C0 = (tau % g.nN) * 128;
  const int tid = threadIdx.x, lane = tid & 63;
  const int l15 = lane & 15;
  const int w = tid >> 6;
  const int srow8 = lane >> 3;
  const int scol8 = ((lane&7) ^ ((lane>>3)&7))*8;
  f32x4 acc[4][2];
  if (g.initMode == 0) {
#pragma unroll
    for (int rt = 0; rt < 4; ++rt)
#pragma unroll
      for (int ct = 0; ct < 2; ++ct)
#pragma unroll
        for (int e = 0; e < 4; ++e) acc[rt][ct][e] = 0.f;
  } else if (g.initMode == 1) {
    const short* C0p = (const short*)g.initp;
#pragma unroll
    for (int rt = 0; rt < 4; ++rt)
#pragma unroll
      for (int ct = 0; ct < 2; ++ct) {
        int c = C0 + w*32 + ct*16 + l15; if (c >= g.N) c = g.N - 1;
#pragma unroll
        for (int e = 0; e < 4; ++e) {
          int r = R0 + rt*16 + 4*(lane>>4) + e; if (r >= g.M) r = g.M - 1;
          acc[rt][ct][e] = bs2f(C0p[(size_t)r*g.ldInit + c]);
        }
      }
  } else {
    const float* v = (const float*)g.initp;
#pragma unroll
    for (int ct = 0; ct < 2; ++ct) {
      int c = C0 + w*32 + ct*16 + l15; if (c >= g.N) c = g.N - 1;
      float vv = v[c];
#pragma unroll
      for (int rt = 0; rt < 4; ++rt)
#pragma unroll
        for (int e = 0; e < 4; ++e) acc[rt][ct][e] = vv;
    }
  }
  auto stage = [&](int kt, int buf) {
    int kb = kt*64;
#pragma unroll
    for (int l = 0; l < 2; ++l) {
      int ra = R0 + w*16 + l*8 + srow8; ra = (ra < g.M) ? ra : g.M - 1;
      glds16(g.A + (size_t)ra*g.lda + kb + scol8, &As[buf*4096 + (w*16 + l*8)*64]);
    }
#pragma unroll
    for (int l = 0; l < 4; ++l) {
      int cb_ = C0 + w*32 + l*8 + srow8; cb_ = (cb_ < g.N) ? cb_ : g.N - 1;
      glds16(g.Y + (size_t)cb_*g.ldy + kb + scol8, &Bs[buf*8192 + (w*32 + l*8)*64]);
    }
  };
  if (g.kd64 > 0) {
    stage(0, 0);
    if (g.kd64 > 1) stage(1, 1);
    int cur = 0;
    for (int kt = 0; kt < g.kd64; ++kt) {
      waitN_bar(kt + 1 >= g.kd64);
#pragma unroll
      for (int kk2 = 0; kk2 < 2; ++kk2) {
        int pos8 = (((lane>>4) | (kk2<<2)) ^ (lane&7))*8;
        short8 xf[4], yf[2];
#pragma unroll
        for (int rt = 0; rt < 4; ++rt) xf[rt] = ld8(&As[cur*4096 + (rt*16 + l15)*64 + pos8]);
#pragma unroll
        for (int ct = 0; ct < 2; ++ct) yf[ct] = ld8(&Bs[cur*8192 + (w*32 + ct*16 + l15)*64 + pos8]);
#pragma unroll
        for (int ct = 0; ct < 2; ++ct)
#pragma unroll
          for (int rt = 0; rt < 4; ++rt) acc[rt][ct] = MF(xf[rt], yf[ct], acc[rt][ct]);
      }
      end_bar();
      if (kt + 2 < g.kd64) stage(kt + 2, cur);
      cur ^= 1;
    }
  }
  if (g.outF) {
#pragma unroll
    for (int rt = 0; rt < 4; ++rt)
#pragma unroll
      for (int ct = 0; ct < 2; ++ct) {
        int c = C0 + w*32 + ct*16 + l15;
        if (c >= g.N) continue;
#pragma unroll
        for (int e = 0; e < 4; ++e) {
          int r = R0 + rt*16 + 4*(lane>>4) + e;
          if (r < g.M)
            g.outF[((size_t)g.Tout*256 + (r & 255))*64 + c] = acc[rt][ct][e] + g.yOffp[(size_t)(r & 255)*64 + c];
        }
      }
  } else {
#pragma unroll
    for (int rt = 0; rt < 4; ++rt)
#pragma unroll
      for (int ct = 0; ct < 2; ++ct) {
        int c = C0 + w*32 + ct*16 + l15;
        if (c >= g.N) continue;
#pragma unroll
        for (int e = 0; e < 4; ++e) {
          int r = R0 + rt*16 + 4*(lane>>4) + e;
          if (r < g.M) g.C[(size_t)r*g.ldc + c] = f2bs(acc[rt][ct][e]);
        }
      }
  }
}

// ---------------- phase 1, 64x128 tiles, BK=64, counted-vmcnt (enc 0..255, dec 256..1279) ----------------
__global__ __launch_bounds__(256) void k_phase1t(
    const short* __restrict__ u1cb, const short* __restrict__ fwst,
    const short* __restrict__ cbD, short* __restrict__ D,
    const short* __restrict__ zenc, const short* __restrict__ rwst,
    const short* __restrict__ cbE, short* __restrict__ Epart)
{
  __shared__ short As[2*4096];
  __shared__ short Bs[2*8192];
  const int lbid = xcd_swz((int)blockIdx.x, (int)gridDim.x);
  const int tid = threadIdx.x, lane = tid & 63;
  const int l15 = lane & 15;
  const int w = tid >> 6;
  const int srow8 = lane >> 3;
  const int scol8 = ((lane&7) ^ ((lane>>3)&7))*8;
  f32x4 acc[4][2];
  if (lbid < 256) {
    const int bb = lbid;
    const int chunk = bb >> 6;             // 0..3
    const int quarter = (bb >> 4) & 3;
    const int R0 = ((bb >> 2) & 3) * 64;
    const int C0 = (bb & 3) * 128;
#pragma unroll
    for (int ct = 0; ct < 2; ++ct) {
      float vv = (quarter == 0) ? bs2f(cbE[C0 + w*32 + ct*16 + l15]) : 0.f;
#pragma unroll
      for (int rt = 0; rt < 4; ++rt)
#pragma unroll
        for (int e = 0; e < 4; ++e) acc[rt][ct][e] = vv;
    }
    auto stage = [&](int kt, int buf) {
      int j = quarter*4 + (kt >> 1), kb = (kt & 1)*64;
#pragma unroll
      for (int l = 0; l < 2; ++l) {
        int ra = R0 + w*16 + l*8 + srow8;
        glds16(zenc + ((size_t)(chunk*16 + j)*256 + ra)*128 + kb + scol8, &As[buf*4096 + (w*16 + l*8)*64]);
      }
#pragma unroll
      for (int l = 0; l < 4; ++l) {
        int cb_ = C0 + w*32 + l*8 + srow8;
        glds16(rwst + ((size_t)j*512 + cb_)*128 + kb + scol8, &Bs[buf*8192 + (w*32 + l*8)*64]);
      }
    };
    stage(0, 0);
    stage(1, 1);
    int cur = 0;
    for (int kt = 0; kt < 8; ++kt) {
      waitN_bar(kt + 1 >= 8);
#pragma unroll
      for (int kk2 = 0; kk2 < 2; ++kk2) {
        int pos8 = (((lane>>4) | (kk2<<2)) ^ (lane&7))*8;
        short8 xf[4], yf[2];
#pragma unroll
        for (int rt = 0; rt < 4; ++rt) xf[rt] = ld8(&As[cur*4096 + (rt*16 + l15)*64 + pos8]);
#pragma unroll
        for (int ct = 0; ct < 2; ++ct) yf[ct] = ld8(&Bs[cur*8192 + (w*32 + ct*16 + l15)*64 + pos8]);
#pragma unroll
        for (int ct = 0; ct < 2; ++ct)
#pragma unroll
          for (int rt = 0; rt < 4; ++rt) acc[rt][ct] = MF(xf[rt], yf[ct], acc[rt][ct]);
      }
      end_bar();
      if (kt + 2 < 8) stage(kt + 2, cur);
      cur ^= 1;
    }
    short* O = Epart + (size_t)(quarter*4 + chunk)*131072;
#pragma unroll
    for (int rt = 0; rt < 4; ++rt)
#pragma unroll
      for (int ct = 0; ct < 2; ++ct) {
        int c = C0 + w*32 + ct*16 + l15;
#pragma unroll
        for (int e = 0; e < 4; ++e) {
          int r = R0 + rt*16 + 4*(lane>>4) + e;
          O[(size_t)r*512 + c] = f2bs(acc[rt][ct][e]);
        }
      }
  } else {
    const int bb = lbid - 256;
    const int chunk = bb >> 4;             // 0..63
    const int R0 = ((bb >> 2) & 3) * 64;
    const int C0 = (bb & 3) * 128;
#pragma unroll
    for (int ct = 0; ct < 2; ++ct) {
      float vv = bs2f(cbD[C0 + w*32 + ct*16 + l15]);
#pragma unroll
      for (int rt = 0; rt < 4; ++rt)
#pragma unroll
        for (int e = 0; e < 4; ++e) acc[rt][ct][e] = vv;
    }
    auto stage = [&](int kt, int buf) {
      int j = kt;
#pragma unroll
      for (int l = 0; l < 2; ++l) {
        int ra = R0 + w*16 + l*8 + srow8;
        glds16(u1cb + ((size_t)(chunk*8 + j)*256 + ra)*64 + scol8, &As[buf*4096 + (w*16 + l*8)*64]);
      }
#pragma unroll
      for (int l = 0; l < 4; ++l) {
        int cb_ = C0 + w*32 + l*8 + srow8;
        glds16(fwst + ((size_t)(8 + j)*512 + cb_)*64 + scol8, &Bs[buf*8192 + (w*32 + l*8)*64]);
      }
    };
    stage(0, 0);
    stage(1, 1);
    int cur = 0;
    for (int kt = 0; kt < 8; ++kt) {
      waitN_bar(kt + 1 >= 8);
#pragma unroll
      for (int kk2 = 0; kk2 < 2; ++kk2) {
        int pos8 = (((lane>>4) | (kk2<<2)) ^ (lane&7))*8;
        short8 xf[4], yf[2];
#pragma unroll
        for (int rt = 0; rt < 4; ++rt) xf[rt] = ld8(&As[cur*4096 + (rt*16 + l15)*64 + pos8]);
#pragma unroll
        for (int ct = 0; ct < 2; ++ct) yf[ct] = ld8(&Bs[cur*8192 + (w*32 + ct*16 + l15)*64 + pos8]);
#pragma unroll
        for (int ct = 0; ct < 2; ++ct)
#pragma unroll
          for (int rt = 0; rt < 4; ++rt) acc[rt][ct] = MF(xf[rt], yf[ct], acc[rt][ct]);
      }
      end_bar();
      if (kt + 2 < 8) stage(kt + 2, cur);
      cur ^= 1;
    }
#pragma unroll
    for (int rt = 0; rt < 4; ++rt)
#pragma unroll
      for (int ct = 0; ct < 2; ++ct) {
        int c = C0 + w*32 + ct*16 + l15;
#pragma unroll
        for (int e = 0; e < 4; ++e) {
          int r = R0 + rt*16 + 4*(lane>>4) + e;
          D[((size_t)chunk*256 + r)*512 + c] = f2bs(acc[rt][ct][e]);
        }
      }
  }
}

// ---------------- add 4 enc partials ----------------
__global__ __launch_bounds__(256) void k_add4(const short* __restrict__ Ep, short* __restrict__ E)
{
  size_t i8 = ((size_t)blockIdx.x*256 + threadIdx.x) * 8;
  int chunk = (int)(i8 >> 17);
  size_t off = i8 & 131071;
  short8 s0 = ld8(Ep + (size_t)(0*4 + chunk)*131072 + off);
  short8 s1 = ld8(Ep + (size_t)(1*4 + chunk)*131072 + off);
  short8 s2 = ld8(Ep + (size_t)(2*4 + chunk)*131072 + off);
  short8 s3 = ld8(Ep + (size_t)(3*4 + chunk)*131072 + off);
  short8 r;
#pragma unroll
  for (int e = 0; e < 8; ++e)
    r[e] = f2bs(bs2f(s0[e]) + bs2f(s1[e]) + bs2f(s2[e]) + bs2f(s3[e]));
  st8(E + (size_t)chunk*131072 + off, r);
}

// ---------------- decode quad-step, BK=64, counted-vmcnt, u-tail folded into pipeline (12 K-tiles) ----------------
__global__ __launch_bounds__(256) void k_xstep4(
    const short* __restrict__ A, short* __restrict__ C,
    const short* __restrict__ u1cb, const short* __restrict__ W4,
    const short* __restrict__ bias4, const float* __restrict__ yOff,
    float* __restrict__ out, int m4, int yOnly)
{
  __shared__ short As[2*4096];
  __shared__ short Bs[2*8192];
  const int lbid = xcd_swz((int)blockIdx.x, (int)gridDim.x);
  const int tid = threadIdx.x, lane = tid & 63;
  const int l15 = lane & 15;
  const int w = tid >> 6;
  const int srow8 = lane >> 3;
  const int scol8 = ((lane&7) ^ ((lane>>3)&7))*8;
  int rtile, ctile;
  if (yOnly) { rtile = lbid >> 1; ctile = 4 + (lbid & 1); }
  else { rtile = lbid / 6; ctile = lbid % 6; }
  const int R0 = rtile * 64, C0 = ctile * 128;
  const int chunk = R0 >> 8;
  f32x4 acc[4][2];
#pragma unroll
  for (int ct = 0; ct < 2; ++ct) {
    float bv = bs2f(bias4[C0 + w*32 + ct*16 + l15]);
#pragma unroll
    for (int rt = 0; rt < 4; ++rt)
#pragma unroll
      for (int e = 0; e < 4; ++e) acc[rt][ct][e] = bv;
  }
  // 12 K-tiles of 64: kt 0..7 from X (A, lda=512); kt 8..11 from u1cb (row (chunk*8+4m4+kt-8)*256+(r&255), 64 wide)
  auto stage = [&](int kt, int buf) {
    if (kt < 8) {
      int kb = kt*64;
#pragma unroll
      for (int l = 0; l < 2; ++l) {
        int ra = R0 + w*16 + l*8 + srow8;
        glds16(A + (size_t)ra*512 + kb + scol8, &As[buf*4096 + (w*16 + l*8)*64]);
      }
    } else {
      int ut = chunk*8 + 4*m4 + (kt - 8);
#pragma unroll
      for (int l = 0; l < 2; ++l) {
        int ra = (R0 + w*16 + l*8 + srow8) & 255;
        glds16(u1cb + ((size_t)ut*256 + ra)*64 + scol8, &As[buf*4096 + (w*16 + l*8)*64]);
      }
    }
    int kb = kt*64;
#pragma unroll
    for (int l = 0; l < 4; ++l) {
      int cb_ = C0 + w*32 + l*8 + srow8;
      glds16(W4 + (size_t)cb_*768 + kb + scol8, &Bs[buf*8192 + (w*32 + l*8)*64]);
    }
  };
  stage(0, 0);
  stage(1, 1);
  int cur = 0;
  for (int kt = 0; kt < 12; ++kt) {
    waitN_bar(kt + 1 >= 12);
#pragma unroll
    for (int kk2 = 0; kk2 < 2; ++kk2) {
      int pos8 = (((lane>>4) | (kk2<<2)) ^ (lane&7))*8;
      short8 xf[4], yf[2];
#pragma unroll
      for (int rt = 0; rt < 4; ++rt) xf[rt] = ld8(&As[cur*4096 + (rt*16 + l15)*64 + pos8]);
#pragma unroll
      for (int ct = 0; ct < 2; ++ct) yf[ct] = ld8(&Bs[cur*8192 + (w*32 + ct*16 + l15)*64 + pos8]);
#pragma unroll
      for (int ct = 0; ct < 2; ++ct)
#pragma unroll
        for (int rt = 0; rt < 4; ++rt) acc[rt][ct] = MF(xf[rt], yf[ct], acc[rt][ct]);
    }
    end_bar();
    if (kt + 2 < 12) stage(kt + 2, cur);
    cur ^= 1;
  }
  if (ctile < 4) {
#pragma unroll
    for (int rt = 0; rt < 4; ++rt)
#pragma unroll
      for (int ct = 0; ct < 2; ++ct) {
        int c = C0 + w*32 + ct*16 + l15;
#pragma unroll
        for (int e = 0; e < 4; ++e) {
          int r = R0 + rt*16 + 4*(lane>>4) + e;
          C[(size_t)r*512 + c] = f2bs(acc[rt][ct][e]);
        }
      }
  } else {
#pragma unroll
    for (int rt = 0; rt < 4; ++rt)
#pragma unroll
      for (int ct = 0; ct < 2; ++ct) {
        int oc = C0 - 512 + w*32 + ct*16 + l15;   // 0..255
        int T = 8*chunk + 4*m4 + 1 + (oc >> 6);
        int col = oc & 63;
#pragma unroll
        for (int e = 0; e < 4; ++e) {
          int rb_ = (R0 + rt*16 + 4*(lane>>4) + e) & 255;
          out[((size_t)T*256 + rb_)*64 + col] = acc[rt][ct][e] + yOff[(size_t)rb_*64 + col];
        }
      }
  }
}

// ---------------- host ----------------
extern "C" void kernel_launch(void* const* d_in, const int* in_sizes, int n_in,
                              void* d_out, int out_size, void* d_ws, size_t ws_size,
                              hipStream_t stream)
{
  const float* Y0   = (const float*)d_in[0];
  const float* U0   = (const float*)d_in[1];
  const float* U1   = (const float*)d_in[2];
  const float* Wenc = (const float*)d_in[3];
  const float* benc = (const float*)d_in[4];
  const float* Wx2x = (const float*)d_in[5];
  const float* bx2x = (const float*)d_in[6];
  const float* Wdec = (const float*)d_in[7];
  const float* bdec = (const float*)d_in[8];
  const float* Wy   = (const float*)d_in[9];
  const float* by   = (const float*)d_in[10];
  float* out = (float*)d_out;
  short* ws = (short*)d_ws;
  const float* yOff = Y0 + (size_t)511*256*64;

  auto MAT = [&](int s) -> short* { return ws + OF_MATS + (size_t)s*262144; };
  auto FTp = [&](int p) -> short* { return ws + OF_FT   + (size_t)p*32768; };
  auto FWs = [&](int j) -> short* { return ws + OF_FWST + (size_t)j*32768; };
  auto RTp = [&](int p) -> short* { return ws + OF_RT   + (size_t)p*65536; };
  auto RWs = [&](int j) -> short* { return ws + OF_RWST + (size_t)j*65536; };
  short* CBB   = ws + OF_CB;
  short* CBEB  = ws + OF_CB + 8192;
  short* CB2   = ws + OF_CB + 2*8192;
  short* CB4   = ws + OF_CB + 3*8192;
  short* CB8   = ws + OF_CB + 4*8192;
  short* CBE2  = ws + OF_CB + 5*8192;
  short* CBE4  = ws + OF_CB + 6*8192;
  short* CBE8  = ws + OF_CB + 7*8192;
  short* CBE16 = ws + OF_CB + 8*8192;
  short* CB3   = ws + OF_CB3;
  short* D8 = ws + OF_D8;
  short* S8 = ws + OF_S8;
  short* WYB = ws + OF_WYB;
  short* W4 = ws + OF_WAUG;
  short* biasb = ws + OF_BIAS;
  short* RX  = W4;
  short* RY1 = W4 + (size_t)512*768;
  short* RY2 = W4 + (size_t)576*768;
  short* RY3 = W4 + (size_t)640*768;
  short* RY4 = W4 + (size_t)704*768;
  auto D8s = [&](int s) -> short* { return D8 + (size_t)s*131072; };
  auto S8s = [&](int s) -> short* { return S8 + (size_t)s*131072; };

  auto addB = [](BBatch& b, const short* A, const short* Y, short* C,
                 int M, int N, int lda, int ldy, int ldc, int im, const void* ip,
                 int ldInit, int kd64) {
    int nN = (N + 127) / 128;
    BItem g{A, Y, C, ip, nullptr, nullptr, M, N, lda, ldy, ldc, kd64, im, b.tiles, nN, 0, ldInit};
    b.it[b.n++] = g; b.tiles += ((M + 63) / 64) * nN;
  };
  auto addSq = [&](BBatch& b, int cs, int xs_, int ys) {
    addB(b, MAT(xs_), MAT(ys), MAT(cs), 512, 512, 512, 512, 512, 0, nullptr, 0, 8);
  };
  auto addFw = [&](BBatch& b, int pq, int wq, int ftp) {
    addB(b, MAT(wq), FTp(ftp), FWs(15 - pq), 512, 64, 512, 512, 64, 0, nullptr, 0, 8);
  };
  auto addFt = [&](BBatch& b, int pdst, int psrc, int wq) {
    addB(b, FTp(psrc), MAT(wq), FTp(pdst), 64, 512, 512, 512, 512, 0, nullptr, 0, 8);
  };
  auto addRw = [&](BBatch& b, int pq, int wq, int rtp) {
    addB(b, MAT(wq), RTp(rtp), RWs(15 - pq), 512, 128, 512, 512, 128, 0, nullptr, 0, 8);
  };
  auto addRt = [&](BBatch& b, int pdst, int psrc, int wq) {
    addB(b, RTp(psrc), MAT(wq), RTp(pdst), 128, 512, 512, 512, 512, 0, nullptr, 0, 8);
  };
  auto addCb = [&](BBatch& b, short* dst, const short* src, int wq) {
    addB(b, src, MAT(wq), dst, 16, 512, 512, 512, 512, 1, src, 512, 8);
  };
  auto addCopy = [&](BBatch& b, const short* src, int ldSrc, short* dst, int M, int N) {
    addB(b, src, src, dst, M, N, ldSrc, ldSrc, 768, 1, src, ldSrc, 0);
  };
  auto addZero = [&](BBatch& b, short* dst, int M, int N) {
    addB(b, WYB, WYB, dst, M, N, 576, 576, 768, 0, nullptr, 0, 0);
  };

  k_prep<<<2048, 256, 0, stream>>>(Y0, U0, U1, Wenc, Wdec, Wx2x, Wy, bdec, benc, ws);

  { BBatch b{}; b.n = 0; b.tiles = 0; // round 1 (q=1)
    addSq(b, SL_AD2W, SL_AD1W, SL_AD1T); addSq(b, SL_AD2T, SL_AD1T, SL_AD1W);
    addSq(b, SL_AE2W, SL_AE1W, SL_AE1T); addSq(b, SL_AE2T, SL_AE1T, SL_AE1W);
    addFw(b, 1, SL_AD1W, 0); addFt(b, 1, 0, SL_AD1W);
    addRw(b, 1, SL_AE1W, 0); addRt(b, 1, 0, SL_AE1W);
    addCb(b, CB2, CBB, SL_AD1W); addCb(b, CBE2, CBEB, SL_AE1W);
    k_bgemm<<<b.tiles, 256, 0, stream>>>(b); }

  { BBatch b{}; b.n = 0; b.tiles = 0; // round 2 (q=2)
    addSq(b, SL_AD4W, SL_AD2W, SL_AD2T); addSq(b, SL_AD4T, SL_AD2T, SL_AD2W);
    addSq(b, SL_AE4W, SL_AE2W, SL_AE2T); addSq(b, SL_AE4T, SL_AE2T, SL_AE2W);
    addFw(b, 2, SL_AD2W, 0); addFw(b, 3, SL_AD2W, 1);
    addFt(b, 2, 0, SL_AD2W); addFt(b, 3, 1, SL_AD2W);
    addRw(b, 2, SL_AE2W, 0); addRw(b, 3, SL_AE2W, 1);
    addRt(b, 2, 0, SL_AE2W); addRt(b, 3, 1, SL_AE2W);
    addCb(b, CB4, CB2, SL_AD2W); addCb(b, CBE4, CBE2, SL_AE2W);
    k_bgemm<<<b.tiles, 256, 0, stream>>>(b); }

  { BBatch b{}; b.n = 0; b.tiles = 0; // round 3 (q=4)
    addSq(b, SL_AD8W, SL_AD4W, SL_AD4T); addSq(b, SL_AD8T, SL_AD4T, SL_AD4W);
    addSq(b, SL_AE8W, SL_AE4W, SL_AE4T); addSq(b, SL_AE8T, SL_AE4T, SL_AE4W);
    for (int p = 0; p < 4; ++p) addFw(b, 4 + p, SL_AD4W, p);
    for (int p = 0; p < 4; ++p) { addRw(b, 4 + p, SL_AE4W, p); addRt(b, 4 + p, p, SL_AE4W); }
    addCb(b, CB8, CB4, SL_AD4W);
    addCb(b, CBE8, CBE4, SL_AE4W);
    k_bgemm<<<b.tiles, 256, 0, stream>>>(b); }

  { BBatch b{}; b.n = 0; b.tiles = 0; // round 4 (q=8)
    addSq(b, SL_AD16W, SL_AD8W, SL_AD8T); addSq(b, SL_AD16T, SL_AD8T, SL_AD8W);
    addSq(b, SL_AE16W, SL_AE8W, SL_AE8T); addSq(b, SL_AE16T, SL_AE8T, SL_AE8W);
    for (int p = 0; p < 8; ++p) addRw(b, 8 + p, SL_AE8W, p);
    addCb(b, CBE16, CBE8, SL_AE8W);
    k_bgemm<<<b.tiles, 256, 0, stream>>>(b); }

  { BBatch b{}; b.n = 0; b.tiles = 0; // round 5: A^32 + asm1 (inputs all from rounds <=3 / prep)
    addSq(b, SL_QD2W, SL_AD16W, SL_AD16T);
    addSq(b, SL_QE2W, SL_AE16W, SL_AE16T);
    addB(b, WYB, MAT(SL_AD1T), RY1, 64, 512, 576, 512, 768, 0, nullptr, 0, 8);        // WyA
    addB(b, WYB, MAT(SL_AD2T), RY2, 64, 512, 576, 512, 768, 0, nullptr, 0, 8);        // WyA2
    addB(b, WYB, FTp(0), RY1 + 512, 64, 64, 576, 512, 768, 1, WYB + 512, 576, 8);     // WyF+Wyu
    addB(b, CBB, MAT(SL_AD2W), CB3, 16, 512, 512, 512, 512, 1, CB2, 512, 8);          // cb3
    addCopy(b, MAT(SL_AD4W), 512, RX, 512, 512);                                      // A4
    addCopy(b, FWs(12), 64, RX + 512, 512, 64);                                       // A3F
    addCopy(b, FWs(13), 64, RX + 576, 512, 64);                                       // A2F
    addCopy(b, FWs(14), 64, RX + 640, 512, 64);                                       // AF
    addCopy(b, FWs(15), 64, RX + 704, 512, 64);                                       // F
    addZero(b, RY1 + 576, 64, 192);
    addZero(b, RY2 + 640, 64, 128);
    addZero(b, RY3 + 704, 64, 64);
    addCopy(b, CB4, 512, biasb, 16, 512);                                             // bias-x = cb4
    addB(b, CBB, WYB, biasb + 512, 16, 64, 512, 576, 768, 2, (const void*)by, 0, 8);  // Wy*cb1+by
    addB(b, CB2, WYB, biasb + 576, 16, 64, 512, 576, 768, 2, (const void*)by, 0, 8);  // Wy*cb2+by
    k_bgemm<<<b.tiles, 256, 0, stream>>>(b); }

  { BBatch b{}; b.n = 0; b.tiles = 0; // asm2 (reads RY1/RY2/CB3 from round 5)
    addB(b, RY2, MAT(SL_AD1T), RY3, 64, 512, 768, 512, 768, 0, nullptr, 0, 8);        // WyA3
    addB(b, RY2, MAT(SL_AD2T), RY4, 64, 512, 768, 512, 768, 0, nullptr, 0, 8);        // WyA4
    addB(b, RY1, FTp(0), RY2 + 512, 64, 64, 768, 512, 768, 0, nullptr, 0, 8);         // WyAF
    addB(b, RY2, FTp(0), RY3 + 512, 64, 64, 768, 512, 768, 0, nullptr, 0, 8);         // WyA2F
    addB(b, CB3, WYB, biasb + 640, 16, 64, 512, 576, 768, 2, (const void*)by, 0, 8);  // Wy*cb3+by
    addB(b, CB4, WYB, biasb + 704, 16, 64, 512, 576, 768, 2, (const void*)by, 0, 8);  // Wy*cb4+by
    k_bgemm<<<b.tiles, 256, 0, stream>>>(b); }

  { BBatch b{}; b.n = 0; b.tiles = 0; // asm3 (reads RY3 / RY*+512 from asm2)
    addB(b, RY3, FTp(0), RY4 + 512, 64, 64, 768, 512, 768, 0, nullptr, 0, 8);         // WyA3F
    addCopy(b, RY1 + 512, 768, RY2 + 576, 64, 64);                                    // WyF+Wyu
    addCopy(b, RY1 + 512, 768, RY3 + 640, 64, 64);
    addCopy(b, RY1 + 512, 768, RY4 + 704, 64, 64);
    addCopy(b, RY2 + 512, 768, RY3 + 576, 64, 64);                                    // WyAF
    addCopy(b, RY2 + 512, 768, RY4 + 640, 64, 64);
    addCopy(b, RY3 + 512, 768, RY4 + 576, 64, 64);                                    // WyA2F
    k_bgemm<<<b.tiles, 256, 0, stream>>>(b); }

  k_phase1t<<<1280, 256, 0, stream>>>(ws + OF_U1CB, ws + OF_FWST, CB8, D8,
                                      ws + OF_ZENC, ws + OF_RWST, CBE16, S8);

  k_add4<<<256, 256, 0, stream>>>(S8, D8s(64));

  { BBatch b{}; b.n = 0; b.tiles = 0; // pairmerge1: d16_m -> S8[2m+1]; E32_i -> D8[68+i]
    for (int m = 0; m < 32; ++m)
      addB(b, D8s(2*m), MAT(SL_AD8W), S8s(2*m+1), 256, 512, 512, 512, 512, 1, D8s(2*m+1), 512, 8);
    for (int i = 0; i < 2; ++i)
      addB(b, D8s(64+2*i), MAT(SL_AE16W), D8s(68+i), 256, 512, 512, 512, 512, 1, D8s(64+2*i+1), 512, 8);
    k_bgemm<<<b.tiles, 256, 0, stream>>>(b); }

  { BBatch b{}; b.n = 0; b.tiles = 0; // pairmerge2: d32_i -> S8[4i+2]; xfin = E32_0*A32e^T + E32_1
    for (int i = 0; i < 16; ++i)
      addB(b, S8s(4*i+1), MAT(SL_AD16W), S8s(4*i+2), 256, 512, 512, 512, 512, 1, S8s(4*i+3), 512, 8);
    addB(b, D8s(68), MAT(SL_QE2W), ws + OF_XFIN, 256, 512, 512, 512, 512, 1, D8s(69), 512, 8);
    k_bgemm<<<b.tiles, 256, 0, stream>>>(b); }

  { BBatch b{}; b.n = 0; b.tiles = 0; // x0hat = xfin * Wx2x^T + bx2x  -> S8[0] directly
    addB(b, ws + OF_XFIN, ws + OF_WX2X, S8s(0), 256, 512, 512, 512, 512, 2, (const void*)bx2x, 0, 8);
    k_bgemm<<<b.tiles, 256, 0, stream>>>(b); }

  { BBatch b{}; b.n = 0; b.tiles = 0; // combine: S32_i -> S8[4i]  (S8[0] already = x0hat)
    addB(b, S8s(0), MAT(SL_QD2W), S8s(4), 256, 512, 512, 512, 512, 1, S8s(2), 512, 8);
    for (int i = 2; i < 16; ++i)
      addB(b, S8s(4*i-6), MAT(SL_QD2W), S8s(4*i), 256, 512, 512, 512, 512, 1, S8s(4*i-2), 512, 8);
    k_bgemm<<<b.tiles, 256, 0, stream>>>(b); }

  { BBatch b{}; b.n = 0; b.tiles = 0; // fill16: S8[4i+2] = S8[4i]*A16^T + d16_{2i}
    for (int i = 0; i < 16; ++i)
      addB(b, S8s(4*i), MAT(SL_AD16W), S8s(4*i+2), 256, 512, 512, 512, 512, 1, S8s(4*i+1), 512, 8);
    k_bgemm<<<b.tiles, 256, 0, stream>>>(b); }

  { BBatch b{}; b.n = 0; b.tiles = 0; // fill8: S8[2j+1] = S8[2j]*A8^T + d8_{2j}; plus yhat0 (T=0)
    for (int j = 0; j < 32; ++j)
      addB(b, S8s(2*j), MAT(SL_AD8W), S8s(2*j+1), 256, 512, 512, 512, 512, 1, D8s(2*j), 512, 8);
    { BItem g{S8s(0), WYB, nullptr, (const void*)by, out, yOff,
              256, 64, 512, 576, 64, 8, 2, b.tiles, 1, 0, 0};
      b.it[b.n++] = g; b.tiles += 4; }
    k_bgemm<<<b.tiles, 256, 0, stream>>>(b); }

  // ---- decode: 2 quad-step launches ----
  short* Xcur = ws + OF_D8;   // D8 region dead after fill8
  k_xstep4<<<1536, 256, 0, stream>>>(S8, Xcur, ws + OF_U1CB, W4, biasb, yOff, out, 0, 0);
  k_xstep4<<<512, 256, 0, stream>>>(Xcur, nullptr, ws + OF_U1CB, W4, biasb, yOff, out, 1, 1);

  (void)in_sizes; (void)n_in; (void)out_size; (void)ws_size;
}

// Round 19
// 235.019 us; speedup vs baseline: 1.2144x; 1.0018x over previous
//
#include <hip/hip_runtime.h>
#include <hip/hip_bf16.h>

typedef __attribute__((ext_vector_type(8))) short short8;
typedef __attribute__((ext_vector_type(4))) float f32x4;
typedef __attribute__((ext_vector_type(4))) float fl4;

#define DEVI static __device__ __forceinline__

DEVI short f2bs(float f) { __hip_bfloat16 h = __float2bfloat16(f); short s; __builtin_memcpy(&s, &h, 2); return s; }
DEVI float bs2f(short s) { __hip_bfloat16 h; __builtin_memcpy(&h, &s, 2); return __bfloat162float(h); }
DEVI short8 ld8(const short* p) { return *reinterpret_cast<const short8*>(p); }
DEVI void st8(short* p, short8 v) { *reinterpret_cast<short8*>(p) = v; }
DEVI f32x4 MF(short8 a, short8 b, f32x4 c) { return __builtin_amdgcn_mfma_f32_16x16x32_bf16(a, b, c, 0, 0, 0); }
DEVI void glds16(const short* g, short* l) {
  __builtin_amdgcn_global_load_lds((const __attribute__((address_space(1))) void*)g,
                                   (__attribute__((address_space(3))) void*)l, 16, 0, 0);
}
// T4 counted-vmcnt barriers: wait own 6/0 outstanding glds, then publish via raw s_barrier
DEVI void waitN_bar(int last) {
  if (last) asm volatile("s_waitcnt vmcnt(0)" ::: "memory");
  else      asm volatile("s_waitcnt vmcnt(6)" ::: "memory");
  __builtin_amdgcn_s_barrier();
  __builtin_amdgcn_sched_barrier(0);
}
DEVI void end_bar() {
  __builtin_amdgcn_sched_barrier(0);
  __builtin_amdgcn_s_barrier();
}
// T1: bijective XCD swizzle (m204)
DEVI int xcd_swz(int bid, int nwg) {
  int q = nwg >> 3, r = nwg & 7;
  int x = bid & 7, i = bid >> 3;
  int base = (x < r) ? x*(q+1) : r*(q+1) + (x - r)*q;
  return base + i;
}

// ---------------- workspace layout (bf16 element offsets) ----------------
constexpr size_t OF_U1CB = 0;              // [512][256][64]
constexpr size_t OF_ZENC = 8388608;        // [64][256][128]
constexpr size_t OF_MATS = 10485760;       // 22 x [512][512]
constexpr size_t OF_FWST = 16252928;       // [16][512][64]
constexpr size_t OF_FT   = 16777216;       // [4][64][512]
constexpr size_t OF_RWST = 16908288;       // [16][512][128]
constexpr size_t OF_RT   = 17956864;       // [8][128][512]
constexpr size_t OF_CB   = 18481152;       // 9 x [16][512]
constexpr size_t OF_WDECB= 18554880;       // [512][576]
constexpr size_t OF_WYB  = 18849792;       // [64][576]
constexpr size_t OF_WX2X = 18886656;       // [512][512]
constexpr size_t OF_D8   = 19148800;       // [70][256][512]
constexpr size_t OF_S8   = 28323840;       // [64][256][512]
constexpr size_t OF_XFIN = 36712448;       // [256][512]
constexpr size_t OF_X0HAT= 36843520;       // [256][512] (unused; x0hat -> S8[0])
constexpr size_t OF_WAUG = 36974592;       // [768][768]
constexpr size_t OF_BIAS = 37564416;       // [16][768]
constexpr size_t OF_CB3  = 37576704;       // [16][512]

enum {
  SL_AD1W=0, SL_AD1T, SL_AD2W, SL_AD2T, SL_AD4W, SL_AD4T, SL_AD8W, SL_AD8T, SL_AD16W, SL_AD16T,
  SL_AE1W, SL_AE1T, SL_AE2W, SL_AE2T, SL_AE4W, SL_AE4T, SL_AE8W, SL_AE8T, SL_AE16W, SL_AE16T,
  SL_QD2W, SL_QE2W
};

// ---------------- prep (vectorized, 8 elems/thread) ----------------
DEVI short8 cvt8(const float* p) {
  fl4 a = *(const fl4*)p, b = *(const fl4*)(p + 4);
  short8 v;
  v[0]=f2bs(a[0]); v[1]=f2bs(a[1]); v[2]=f2bs(a[2]); v[3]=f2bs(a[3]);
  v[4]=f2bs(b[0]); v[5]=f2bs(b[1]); v[6]=f2bs(b[2]); v[7]=f2bs(b[3]);
  return v;
}
DEVI short8 sub8(const float* p, const float* o) {
  fl4 a = *(const fl4*)p, b = *(const fl4*)(p + 4);
  fl4 c = *(const fl4*)o, d = *(const fl4*)(o + 4);
  short8 v;
  v[0]=f2bs(a[0]-c[0]); v[1]=f2bs(a[1]-c[1]); v[2]=f2bs(a[2]-c[2]); v[3]=f2bs(a[3]-c[3]);
  v[4]=f2bs(b[0]-d[0]); v[5]=f2bs(b[1]-d[1]); v[6]=f2bs(b[2]-d[2]); v[7]=f2bs(b[3]-d[3]);
  return v;
}
DEVI short8 gath8(const float* p, int stride) {
  short8 v;
#pragma unroll
  for (int e = 0; e < 8; ++e) v[e] = f2bs(p[(size_t)e*stride]);
  return v;
}

__global__ __launch_bounds__(256) void k_prep(
    const float* __restrict__ Y0, const float* __restrict__ U0, const float* __restrict__ U1,
    const float* __restrict__ Wenc, const float* __restrict__ Wdec,
    const float* __restrict__ Wx2x, const float* __restrict__ Wy,
    const float* __restrict__ bdec, const float* __restrict__ benc,
    short* __restrict__ ws)
{
  const size_t total8 = 12341248 / 8;
  for (size_t gidx = (size_t)blockIdx.x*256 + threadIdx.x; gidx < total8; gidx += (size_t)gridDim.x*256) {
    size_t i = gidx * 8;
    short8 v; size_t dst;
    if (i < 8388608) {
      int r = (int)((i >> 6) & 255), u = (int)(i & 63);
      v = sub8(U1 + i, U0 + (size_t)(511*256 + r)*64 + u);
      dst = OF_U1CB + i;
    } else if ((i -= 8388608) < 2097152) {
      int tt = (int)(i >> 15), r = (int)((i >> 7) & 255), z = (int)(i & 127);
      int t = 448 + tt;
      if (z < 64) v = sub8(Y0 + ((size_t)t*256 + r)*64 + z, Y0 + (size_t)(511*256 + r)*64 + z);
      else        v = sub8(U0 + ((size_t)t*256 + r)*64 + (z-64), U0 + (size_t)(511*256 + r)*64 + (z-64));
      dst = OF_ZENC + i;
    } else if ((i -= 2097152) < 262144) {
      v = cvt8(Wdec + (size_t)(i>>9)*576 + (i&511));
      dst = OF_MATS + (size_t)SL_AD1W*262144 + i;
    } else if ((i -= 262144) < 262144) {
      v = gath8(Wdec + (size_t)(i&511)*576 + (i>>9), 576);
      dst = OF_MATS + (size_t)SL_AD1T*262144 + i;
    } else if ((i -= 262144) < 262144) {
      v = cvt8(Wenc + (size_t)(i>>9)*640 + (i&511));
      dst = OF_MATS + (size_t)SL_AE1W*262144 + i;
    } else if ((i -= 262144) < 262144) {
      v = gath8(Wenc + (size_t)(i&511)*640 + (i>>9), 640);
      dst = OF_MATS + (size_t)SL_AE1T*262144 + i;
    } else if ((i -= 262144) < 294912) {
      v = cvt8(Wdec + i);
      dst = OF_WDECB + i;
    } else if ((i -= 294912) < 36864) {
      v = cvt8(Wy + i);
      dst = OF_WYB + i;
    } else if ((i -= 36864) < 262144) {
      v = cvt8(Wx2x + i);
      dst = OF_WX2X + i;
    } else if ((i -= 262144) < 32768) {
      v = gath8(Wdec + (size_t)(i&511)*576 + 512 + (i>>9), 576);
      dst = OF_FT + i;
    } else if ((i -= 32768) < 32768) {
      v = cvt8(Wdec + (size_t)(i>>6)*576 + 512 + (i&63));
      dst = OF_FWST + (size_t)15*32768 + i;
    } else if ((i -= 32768) < 65536) {
      v = gath8(Wenc + (size_t)(i&511)*640 + 512 + (i>>9), 640);
      dst = OF_RT + i;
    } else if ((i -= 65536) < 65536) {
      v = cvt8(Wenc + (size_t)(i>>7)*640 + 512 + (i&127));
      dst = OF_RWST + (size_t)15*65536 + i;
    } else if ((i -= 65536) < 8192) {
      if (i < 512) v = cvt8(bdec + i); else { for (int e = 0; e < 8; ++e) v[e] = 0; }
      dst = OF_CB + i;                    // CB_B
    } else {
      i -= 8192;
      if (i < 512) v = cvt8(benc + i); else { for (int e = 0; e < 8; ++e) v[e] = 0; }
      dst = OF_CB + 8192 + i;             // CBE_B
    }
    st8(ws + dst, v);
  }
}

// ---------------- batched LDS-tiled GEMM, 64x128 tiles, BK=64, counted-vmcnt pipeline + T5 setprio ----------------
struct BItem {
  const short* A; const short* Y; short* C; const void* initp;
  float* outF; const float* yOffp;
  int M, N, lda, ldy, ldc, kd64, initMode, tileStart, nN, Tout, ldInit;
};
struct BBatch { BItem it[36]; int n; int tiles; };

__global__ __launch_bounds__(256) void k_bgemm(BBatch b)
{
  __shared__ short As[2*4096];
  __shared__ short Bs[2*8192];
  const int lbid = xcd_swz((int)blockIdx.x, (int)gridDim.x);
  int ii = 0;
  for (int t = 1; t < b.n; ++t) if (lbid >= b.it[t].tileStart) ii = t;
  BItem g = b.it[ii];
  const int tau = lbid - g.tileStart;
  const int R0 = (tau / g.nN) * 64;
  const int C0 = (tau % g.nN) * 128;
  const int tid = threadIdx.x, lane = tid & 63;
  const int l15 = lane & 15;
  const int w = tid >> 6;
  const int srow8 = lane >> 3;
  const int scol8 = ((lane&7) ^ ((lane>>3)&7))*8;
  f32x4 acc[4][2];
  if (g.initMode == 0) {
#pragma unroll
    for (int rt = 0; rt < 4; ++rt)
#pragma unroll
      for (int ct = 0; ct < 2; ++ct)
#pragma unroll
        for (int e = 0; e < 4; ++e) acc[rt][ct][e] = 0.f;
  } else if (g.initMode == 1) {
    const short* C0p = (const short*)g.initp;
#pragma unroll
    for (int rt = 0; rt < 4; ++rt)
#pragma unroll
      for (int ct = 0; ct < 2; ++ct) {
        int c = C0 + w*32 + ct*16 + l15; if (c >= g.N) c = g.N - 1;
#pragma unroll
        for (int e = 0; e < 4; ++e) {
          int r = R0 + rt*16 + 4*(lane>>4) + e; if (r >= g.M) r = g.M - 1;
          acc[rt][ct][e] = bs2f(C0p[(size_t)r*g.ldInit + c]);
        }
      }
  } else {
    const float* v = (const float*)g.initp;
#pragma unroll
    for (int ct = 0; ct < 2; ++ct) {
      int c = C0 + w*32 + ct*16 + l15; if (c >= g.N) c = g.N - 1;
      float vv = v[c];
#pragma unroll
      for (int rt = 0; rt < 4; ++rt)
#pragma unroll
        for (int e = 0; e < 4; ++e) acc[rt][ct][e] = vv;
    }
  }
  auto stage = [&](int kt, int buf) {
    int kb = kt*64;
#pragma unroll
    for (int l = 0; l < 2; ++l) {
      int ra = R0 + w*16 + l*8 + srow8; ra = (ra < g.M) ? ra : g.M - 1;
      glds16(g.A + (size_t)ra*g.lda + kb + scol8, &As[buf*4096 + (w*16 + l*8)*64]);
    }
#pragma unroll
    for (int l = 0; l < 4; ++l) {
      int cb_ = C0 + w*32 + l*8 + srow8; cb_ = (cb_ < g.N) ? cb_ : g.N - 1;
      glds16(g.Y + (size_t)cb_*g.ldy + kb + scol8, &Bs[buf*8192 + (w*32 + l*8)*64]);
    }
  };
  if (g.kd64 > 0) {
    stage(0, 0);
    if (g.kd64 > 1) stage(1, 1);
    int cur = 0;
    for (int kt = 0; kt < g.kd64; ++kt) {
      waitN_bar(kt + 1 >= g.kd64);
      __builtin_amdgcn_s_setprio(1);
#pragma unroll
      for (int kk2 = 0; kk2 < 2; ++kk2) {
        int pos8 = (((lane>>4) | (kk2<<2)) ^ (lane&7))*8;
        short8 xf[4], yf[2];
#pragma unroll
        for (int rt = 0; rt < 4; ++rt) xf[rt] = ld8(&As[cur*4096 + (rt*16 + l15)*64 + pos8]);
#pragma unroll
        for (int ct = 0; ct < 2; ++ct) yf[ct] = ld8(&Bs[cur*8192 + (w*32 + ct*16 + l15)*64 + pos8]);
#pragma unroll
        for (int ct = 0; ct < 2; ++ct)
#pragma unroll
          for (int rt = 0; rt < 4; ++rt) acc[rt][ct] = MF(xf[rt], yf[ct], acc[rt][ct]);
      }
      __builtin_amdgcn_s_setprio(0);
      end_bar();
      if (kt + 2 < g.kd64) stage(kt + 2, cur);
      cur ^= 1;
    }
  }
  if (g.outF) {
#pragma unroll
    for (int rt = 0; rt < 4; ++rt)
#pragma unroll
      for (int ct = 0; ct < 2; ++ct) {
        int c = C0 + w*32 + ct*16 + l15;
        if (c >= g.N) continue;
#pragma unroll
        for (int e = 0; e < 4; ++e) {
          int r = R0 + rt*16 + 4*(lane>>4) + e;
          if (r < g.M)
            g.outF[((size_t)g.Tout*256 + (r & 255))*64 + c] = acc[rt][ct][e] + g.yOffp[(size_t)(r & 255)*64 + c];
        }
      }
  } else {
#pragma unroll
    for (int rt = 0; rt < 4; ++rt)
#pragma unroll
      for (int ct = 0; ct < 2; ++ct) {
        int c = C0 + w*32 + ct*16 + l15;
        if (c >= g.N) continue;
#pragma unroll
        for (int e = 0; e < 4; ++e) {
          int r = R0 + rt*16 + 4*(lane>>4) + e;
          if (r < g.M) g.C[(size_t)r*g.ldc + c] = f2bs(acc[rt][ct][e]);
        }
      }
  }
}

// ---------------- phase 1, 64x128 tiles, BK=64, counted-vmcnt + T5 (enc 0..255, dec 256..1279) ----------------
__global__ __launch_bounds__(256) void k_phase1t(
    const short* __restrict__ u1cb, const short* __restrict__ fwst,
    const short* __restrict__ cbD, short* __restrict__ D,
    const short* __restrict__ zenc, const short* __restrict__ rwst,
    const short* __restrict__ cbE, short* __restrict__ Epart)
{
  __shared__ short As[2*4096];
  __shared__ short Bs[2*8192];
  const int lbid = xcd_swz((int)blockIdx.x, (int)gridDim.x);
  const int tid = threadIdx.x, lane = tid & 63;
  const int l15 = lane & 15;
  const int w = tid >> 6;
  const int srow8 = lane >> 3;
  const int scol8 = ((lane&7) ^ ((lane>>3)&7))*8;
  f32x4 acc[4][2];
  if (lbid < 256) {
    const int bb = lbid;
    const int chunk = bb >> 6;             // 0..3
    const int quarter = (bb >> 4) & 3;
    const int R0 = ((bb >> 2) & 3) * 64;
    const int C0 = (bb & 3) * 128;
#pragma unroll
    for (int ct = 0; ct < 2; ++ct) {
      float vv = (quarter == 0) ? bs2f(cbE[C0 + w*32 + ct*16 + l15]) : 0.f;
#pragma unroll
      for (int rt = 0; rt < 4; ++rt)
#pragma unroll
        for (int e = 0; e < 4; ++e) acc[rt][ct][e] = vv;
    }
    auto stage = [&](int kt, int buf) {
      int j = quarter*4 + (kt >> 1), kb = (kt & 1)*64;
#pragma unroll
      for (int l = 0; l < 2; ++l) {
        int ra = R0 + w*16 + l*8 + srow8;
        glds16(zenc + ((size_t)(chunk*16 + j)*256 + ra)*128 + kb + scol8, &As[buf*4096 + (w*16 + l*8)*64]);
      }
#pragma unroll
      for (int l = 0; l < 4; ++l) {
        int cb_ = C0 + w*32 + l*8 + srow8;
        glds16(rwst + ((size_t)j*512 + cb_)*128 + kb + scol8, &Bs[buf*8192 + (w*32 + l*8)*64]);
      }
    };
    stage(0, 0);
    stage(1, 1);
    int cur = 0;
    for (int kt = 0; kt < 8; ++kt) {
      waitN_bar(kt + 1 >= 8);
      __builtin_amdgcn_s_setprio(1);
#pragma unroll
      for (int kk2 = 0; kk2 < 2; ++kk2) {
        int pos8 = (((lane>>4) | (kk2<<2)) ^ (lane&7))*8;
        short8 xf[4], yf[2];
#pragma unroll
        for (int rt = 0; rt < 4; ++rt) xf[rt] = ld8(&As[cur*4096 + (rt*16 + l15)*64 + pos8]);
#pragma unroll
        for (int ct = 0; ct < 2; ++ct) yf[ct] = ld8(&Bs[cur*8192 + (w*32 + ct*16 + l15)*64 + pos8]);
#pragma unroll
        for (int ct = 0; ct < 2; ++ct)
#pragma unroll
          for (int rt = 0; rt < 4; ++rt) acc[rt][ct] = MF(xf[rt], yf[ct], acc[rt][ct]);
      }
      __builtin_amdgcn_s_setprio(0);
      end_bar();
      if (kt + 2 < 8) stage(kt + 2, cur);
      cur ^= 1;
    }
    short* O = Epart + (size_t)(quarter*4 + chunk)*131072;
#pragma unroll
    for (int rt = 0; rt < 4; ++rt)
#pragma unroll
      for (int ct = 0; ct < 2; ++ct) {
        int c = C0 + w*32 + ct*16 + l15;
#pragma unroll
        for (int e = 0; e < 4; ++e) {
          int r = R0 + rt*16 + 4*(lane>>4) + e;
          O[(size_t)r*512 + c] = f2bs(acc[rt][ct][e]);
        }
      }
  } else {
    const int bb = lbid - 256;
    const int chunk = bb >> 4;             // 0..63
    const int R0 = ((bb >> 2) & 3) * 64;
    const int C0 = (bb & 3) * 128;
#pragma unroll
    for (int ct = 0; ct < 2; ++ct) {
      float vv = bs2f(cbD[C0 + w*32 + ct*16 + l15]);
#pragma unroll
      for (int rt = 0; rt < 4; ++rt)
#pragma unroll
        for (int e = 0; e < 4; ++e) acc[rt][ct][e] = vv;
    }
    auto stage = [&](int kt, int buf) {
      int j = kt;
#pragma unroll
      for (int l = 0; l < 2; ++l) {
        int ra = R0 + w*16 + l*8 + srow8;
        glds16(u1cb + ((size_t)(chunk*8 + j)*256 + ra)*64 + scol8, &As[buf*4096 + (w*16 + l*8)*64]);
      }
#pragma unroll
      for (int l = 0; l < 4; ++l) {
        int cb_ = C0 + w*32 + l*8 + srow8;
        glds16(fwst + ((size_t)(8 + j)*512 + cb_)*64 + scol8, &Bs[buf*8192 + (w*32 + l*8)*64]);
      }
    };
    stage(0, 0);
    stage(1, 1);
    int cur = 0;
    for (int kt = 0; kt < 8; ++kt) {
      waitN_bar(kt + 1 >= 8);
      __builtin_amdgcn_s_setprio(1);
#pragma unroll
      for (int kk2 = 0; kk2 < 2; ++kk2) {
        int pos8 = (((lane>>4) | (kk2<<2)) ^ (lane&7))*8;
        short8 xf[4], yf[2];
#pragma unroll
        for (int rt = 0; rt < 4; ++rt) xf[rt] = ld8(&As[cur*4096 + (rt*16 + l15)*64 + pos8]);
#pragma unroll
        for (int ct = 0; ct < 2; ++ct) yf[ct] = ld8(&Bs[cur*8192 + (w*32 + ct*16 + l15)*64 + pos8]);
#pragma unroll
        for (int ct = 0; ct < 2; ++ct)
#pragma unroll
          for (int rt = 0; rt < 4; ++rt) acc[rt][ct] = MF(xf[rt], yf[ct], acc[rt][ct]);
      }
      __builtin_amdgcn_s_setprio(0);
      end_bar();
      if (kt + 2 < 8) stage(kt + 2, cur);
      cur ^= 1;
    }
#pragma unroll
    for (int rt = 0; rt < 4; ++rt)
#pragma unroll
      for (int ct = 0; ct < 2; ++ct) {
        int c = C0 + w*32 + ct*16 + l15;
#pragma unroll
        for (int e = 0; e < 4; ++e) {
          int r = R0 + rt*16 + 4*(lane>>4) + e;
          D[((size_t)chunk*256 + r)*512 + c] = f2bs(acc[rt][ct][e]);
        }
      }
  }
}

// ---------------- add 4 enc partials ----------------
__global__ __launch_bounds__(256) void k_add4(const short* __restrict__ Ep, short* __restrict__ E)
{
  size_t i8 = ((size_t)blockIdx.x*256 + threadIdx.x) * 8;
  int chunk = (int)(i8 >> 17);
  size_t off = i8 & 131071;
  short8 s0 = ld8(Ep + (size_t)(0*4 + chunk)*131072 + off);
  short8 s1 = ld8(Ep + (size_t)(1*4 + chunk)*131072 + off);
  short8 s2 = ld8(Ep + (size_t)(2*4 + chunk)*131072 + off);
  short8 s3 = ld8(Ep + (size_t)(3*4 + chunk)*131072 + off);
  short8 r;
#pragma unroll
  for (int e = 0; e < 8; ++e)
    r[e] = f2bs(bs2f(s0[e]) + bs2f(s1[e]) + bs2f(s2[e]) + bs2f(s3[e]));
  st8(E + (size_t)chunk*131072 + off, r);
}

// ---------------- decode quad-step, BK=64, counted-vmcnt + T5, u-tail folded (12 K-tiles) ----------------
__global__ __launch_bounds__(256) void k_xstep4(
    const short* __restrict__ A, short* __restrict__ C,
    const short* __restrict__ u1cb, const short* __restrict__ W4,
    const short* __restrict__ bias4, const float* __restrict__ yOff,
    float* __restrict__ out, int m4, int yOnly)
{
  __shared__ short As[2*4096];
  __shared__ short Bs[2*8192];
  const int lbid = xcd_swz((int)blockIdx.x, (int)gridDim.x);
  const int tid = threadIdx.x, lane = tid & 63;
  const int l15 = lane & 15;
  const int w = tid >> 6;
  const int srow8 = lane >> 3;
  const int scol8 = ((lane&7) ^ ((lane>>3)&7))*8;
  int rtile, ctile;
  if (yOnly) { rtile = lbid >> 1; ctile = 4 + (lbid & 1); }
  else { rtile = lbid / 6; ctile = lbid % 6; }
  const int R0 = rtile * 64, C0 = ctile * 128;
  const int chunk = R0 >> 8;
  f32x4 acc[4][2];
#pragma unroll
  for (int ct = 0; ct < 2; ++ct) {
    float bv = bs2f(bias4[C0 + w*32 + ct*16 + l15]);
#pragma unroll
    for (int rt = 0; rt < 4; ++rt)
#pragma unroll
      for (int e = 0; e < 4; ++e) acc[rt][ct][e] = bv;
  }
  // 12 K-tiles of 64: kt 0..7 from X (A, lda=512); kt 8..11 from u1cb
  auto stage = [&](int kt, int buf) {
    if (kt < 8) {
      int kb = kt*64;
#pragma unroll
      for (int l = 0; l < 2; ++l) {
        int ra = R0 + w*16 + l*8 + srow8;
        glds16(A + (size_t)ra*512 + kb + scol8, &As[buf*4096 + (w*16 + l*8)*64]);
      }
    } else {
      int ut = chunk*8 + 4*m4 + (kt - 8);
#pragma unroll
      for (int l = 0; l < 2; ++l) {
        int ra = (R0 + w*16 + l*8 + srow8) & 255;
        glds16(u1cb + ((size_t)ut*256 + ra)*64 + scol8, &As[buf*4096 + (w*16 + l*8)*64]);
      }
    }
    int kb = kt*64;
#pragma unroll
    for (int l = 0; l < 4; ++l) {
      int cb_ = C0 + w*32 + l*8 + srow8;
      glds16(W4 + (size_t)cb_*768 + kb + scol8, &Bs[buf*8192 + (w*32 + l*8)*64]);
    }
  };
  stage(0, 0);
  stage(1, 1);
  int cur = 0;
  for (int kt = 0; kt < 12; ++kt) {
    waitN_bar(kt + 1 >= 12);
    __builtin_amdgcn_s_setprio(1);
#pragma unroll
    for (int kk2 = 0; kk2 < 2; ++kk2) {
      int pos8 = (((lane>>4) | (kk2<<2)) ^ (lane&7))*8;
      short8 xf[4], yf[2];
#pragma unroll
      for (int rt = 0; rt < 4; ++rt) xf[rt] = ld8(&As[cur*4096 + (rt*16 + l15)*64 + pos8]);
#pragma unroll
      for (int ct = 0; ct < 2; ++ct) yf[ct] = ld8(&Bs[cur*8192 + (w*32 + ct*16 + l15)*64 + pos8]);
#pragma unroll
      for (int ct = 0; ct < 2; ++ct)
#pragma unroll
        for (int rt = 0; rt < 4; ++rt) acc[rt][ct] = MF(xf[rt], yf[ct], acc[rt][ct]);
    }
    __builtin_amdgcn_s_setprio(0);
    end_bar();
    if (kt + 2 < 12) stage(kt + 2, cur);
    cur ^= 1;
  }
  if (ctile < 4) {
#pragma unroll
    for (int rt = 0; rt < 4; ++rt)
#pragma unroll
      for (int ct = 0; ct < 2; ++ct) {
        int c = C0 + w*32 + ct*16 + l15;
#pragma unroll
        for (int e = 0; e < 4; ++e) {
          int r = R0 + rt*16 + 4*(lane>>4) + e;
          C[(size_t)r*512 + c] = f2bs(acc[rt][ct][e]);
        }
      }
  } else {
#pragma unroll
    for (int rt = 0; rt < 4; ++rt)
#pragma unroll
      for (int ct = 0; ct < 2; ++ct) {
        int oc = C0 - 512 + w*32 + ct*16 + l15;   // 0..255
        int T = 8*chunk + 4*m4 + 1 + (oc >> 6);
        int col = oc & 63;
#pragma unroll
        for (int e = 0; e < 4; ++e) {
          int rb_ = (R0 + rt*16 + 4*(lane>>4) + e) & 255;
          out[((size_t)T*256 + rb_)*64 + col] = acc[rt][ct][e] + yOff[(size_t)rb_*64 + col];
        }
      }
  }
}

// ---------------- host ----------------
extern "C" void kernel_launch(void* const* d_in, const int* in_sizes, int n_in,
                              void* d_out, int out_size, void* d_ws, size_t ws_size,
                              hipStream_t stream)
{
  const float* Y0   = (const float*)d_in[0];
  const float* U0   = (const float*)d_in[1];
  const float* U1   = (const float*)d_in[2];
  const float* Wenc = (const float*)d_in[3];
  const float* benc = (const float*)d_in[4];
  const float* Wx2x = (const float*)d_in[5];
  const float* bx2x = (const float*)d_in[6];
  const float* Wdec = (const float*)d_in[7];
  const float* bdec = (const float*)d_in[8];
  const float* Wy   = (const float*)d_in[9];
  const float* by   = (const float*)d_in[10];
  float* out = (float*)d_out;
  short* ws = (short*)d_ws;
  const float* yOff = Y0 + (size_t)511*256*64;

  auto MAT = [&](int s) -> short* { return ws + OF_MATS + (size_t)s*262144; };
  auto FTp = [&](int p) -> short* { return ws + OF_FT   + (size_t)p*32768; };
  auto FWs = [&](int j) -> short* { return ws + OF_FWST + (size_t)j*32768; };
  auto RTp = [&](int p) -> short* { return ws + OF_RT   + (size_t)p*65536; };
  auto RWs = [&](int j) -> short* { return ws + OF_RWST + (size_t)j*65536; };
  short* CBB   = ws + OF_CB;
  short* CBEB  = ws + OF_CB + 8192;
  short* CB2   = ws + OF_CB + 2*8192;
  short* CB4   = ws + OF_CB + 3*8192;
  short* CB8   = ws + OF_CB + 4*8192;
  short* CBE2  = ws + OF_CB + 5*8192;
  short* CBE4  = ws + OF_CB + 6*8192;
  short* CBE8  = ws + OF_CB + 7*8192;
  short* CBE16 = ws + OF_CB + 8*8192;
  short* CB3   = ws + OF_CB3;
  short* D8 = ws + OF_D8;
  short* S8 = ws + OF_S8;
  short* WYB = ws + OF_WYB;
  short* W4 = ws + OF_WAUG;
  short* biasb = ws + OF_BIAS;
  short* RX  = W4;
  short* RY1 = W4 + (size_t)512*768;
  short* RY2 = W4 + (size_t)576*768;
  short* RY3 = W4 + (size_t)640*768;
  short* RY4 = W4 + (size_t)704*768;
  auto D8s = [&](int s) -> short* { return D8 + (size_t)s*131072; };
  auto S8s = [&](int s) -> short* { return S8 + (size_t)s*131072; };

  auto addB = [](BBatch& b, const short* A, const short* Y, short* C,
                 int M, int N, int lda, int ldy, int ldc, int im, const void* ip,
                 int ldInit, int kd64) {
    int nN = (N + 127) / 128;
    BItem g{A, Y, C, ip, nullptr, nullptr, M, N, lda, ldy, ldc, kd64, im, b.tiles, nN, 0, ldInit};
    b.it[b.n++] = g; b.tiles += ((M + 63) / 64) * nN;
  };
  auto addSq = [&](BBatch& b, int cs, int xs_, int ys) {
    addB(b, MAT(xs_), MAT(ys), MAT(cs), 512, 512, 512, 512, 512, 0, nullptr, 0, 8);
  };
  auto addFw = [&](BBatch& b, int pq, int wq, int ftp) {
    addB(b, MAT(wq), FTp(ftp), FWs(15 - pq), 512, 64, 512, 512, 64, 0, nullptr, 0, 8);
  };
  auto addFt = [&](BBatch& b, int pdst, int psrc, int wq) {
    addB(b, FTp(psrc), MAT(wq), FTp(pdst), 64, 512, 512, 512, 512, 0, nullptr, 0, 8);
  };
  auto addRw = [&](BBatch& b, int pq, int wq, int rtp) {
    addB(b, MAT(wq), RTp(rtp), RWs(15 - pq), 512, 128, 512, 512, 128, 0, nullptr, 0, 8);
  };
  auto addRt = [&](BBatch& b, int pdst, int psrc, int wq) {
    addB(b, RTp(psrc), MAT(wq), RTp(pdst), 128, 512, 512, 512, 512, 0, nullptr, 0, 8);
  };
  auto addCb = [&](BBatch& b, short* dst, const short* src, int wq) {
    addB(b, src, MAT(wq), dst, 16, 512, 512, 512, 512, 1, src, 512, 8);
  };
  auto addCopy = [&](BBatch& b, const short* src, int ldSrc, short* dst, int M, int N) {
    addB(b, src, src, dst, M, N, ldSrc, ldSrc, 768, 1, src, ldSrc, 0);
  };
  auto addZero = [&](BBatch& b, short* dst, int M, int N) {
    addB(b, WYB, WYB, dst, M, N, 576, 576, 768, 0, nullptr, 0, 0);
  };

  k_prep<<<2048, 256, 0, stream>>>(Y0, U0, U1, Wenc, Wdec, Wx2x, Wy, bdec, benc, ws);

  { BBatch b{}; b.n = 0; b.tiles = 0; // round 1 (q=1)
    addSq(b, SL_AD2W, SL_AD1W, SL_AD1T); addSq(b, SL_AD2T, SL_AD1T, SL_AD1W);
    addSq(b, SL_AE2W, SL_AE1W, SL_AE1T); addSq(b, SL_AE2T, SL_AE1T, SL_AE1W);
    addFw(b, 1, SL_AD1W, 0); addFt(b, 1, 0, SL_AD1W);
    addRw(b, 1, SL_AE1W, 0); addRt(b, 1, 0, SL_AE1W);
    addCb(b, CB2, CBB, SL_AD1W); addCb(b, CBE2, CBEB, SL_AE1W);
    k_bgemm<<<b.tiles, 256, 0, stream>>>(b); }

  { BBatch b{}; b.n = 0; b.tiles = 0; // round 2 (q=2)
    addSq(b, SL_AD4W, SL_AD2W, SL_AD2T); addSq(b, SL_AD4T, SL_AD2T, SL_AD2W);
    addSq(b, SL_AE4W, SL_AE2W, SL_AE2T); addSq(b, SL_AE4T, SL_AE2T, SL_AE2W);
    addFw(b, 2, SL_AD2W, 0); addFw(b, 3, SL_AD2W, 1);
    addFt(b, 2, 0, SL_AD2W); addFt(b, 3, 1, SL_AD2W);
    addRw(b, 2, SL_AE2W, 0); addRw(b, 3, SL_AE2W, 1);
    addRt(b, 2, 0, SL_AE2W); addRt(b, 3, 1, SL_AE2W);
    addCb(b, CB4, CB2, SL_AD2W); addCb(b, CBE4, CBE2, SL_AE2W);
    k_bgemm<<<b.tiles, 256, 0, stream>>>(b); }

  { BBatch b{}; b.n = 0; b.tiles = 0; // round 3 (q=4)
    addSq(b, SL_AD8W, SL_AD4W, SL_AD4T); addSq(b, SL_AD8T, SL_AD4T, SL_AD4W);
    addSq(b, SL_AE8W, SL_AE4W, SL_AE4T); addSq(b, SL_AE8T, SL_AE4T, SL_AE4W);
    for (int p = 0; p < 4; ++p) addFw(b, 4 + p, SL_AD4W, p);
    for (int p = 0; p < 4; ++p) { addRw(b, 4 + p, SL_AE4W, p); addRt(b, 4 + p, p, SL_AE4W); }
    addCb(b, CB8, CB4, SL_AD4W);
    addCb(b, CBE8, CBE4, SL_AE4W);
    k_bgemm<<<b.tiles, 256, 0, stream>>>(b); }

  { BBatch b{}; b.n = 0; b.tiles = 0; // round 4 (q=8)
    addSq(b, SL_AD16W, SL_AD8W, SL_AD8T); addSq(b, SL_AD16T, SL_AD8T, SL_AD8W);
    addSq(b, SL_AE16W, SL_AE8W, SL_AE8T); addSq(b, SL_AE16T, SL_AE8T, SL_AE8W);
    for (int p = 0; p < 8; ++p) addRw(b, 8 + p, SL_AE8W, p);
    addCb(b, CBE16, CBE8, SL_AE8W);
    k_bgemm<<<b.tiles, 256, 0, stream>>>(b); }

  { BBatch b{}; b.n = 0; b.tiles = 0; // round 5: A^32 + asm1 (inputs all from rounds <=3 / prep)
    addSq(b, SL_QD2W, SL_AD16W, SL_AD16T);
    addSq(b, SL_QE2W, SL_AE16W, SL_AE16T);
    addB(b, WYB, MAT(SL_AD1T), RY1, 64, 512, 576, 512, 768, 0, nullptr, 0, 8);        // WyA
    addB(b, WYB, MAT(SL_AD2T), RY2, 64, 512, 576, 512, 768, 0, nullptr, 0, 8);        // WyA2
    addB(b, WYB, FTp(0), RY1 + 512, 64, 64, 576, 512, 768, 1, WYB + 512, 576, 8);     // WyF+Wyu
    addB(b, CBB, MAT(SL_AD2W), CB3, 16, 512, 512, 512, 512, 1, CB2, 512, 8);          // cb3
    addCopy(b, MAT(SL_AD4W), 512, RX, 512, 512);                                      // A4
    addCopy(b, FWs(12), 64, RX + 512, 512, 64);                                       // A3F
    addCopy(b, FWs(13), 64, RX + 576, 512, 64);                                       // A2F
    addCopy(b, FWs(14), 64, RX + 640, 512, 64);                                       // AF
    addCopy(b, FWs(15), 64, RX + 704, 512, 64);                                       // F
    addZero(b, RY1 + 576, 64, 192);
    addZero(b, RY2 + 640, 64, 128);
    addZero(b, RY3 + 704, 64, 64);
    addCopy(b, CB4, 512, biasb, 16, 512);                                             // bias-x = cb4
    addB(b, CBB, WYB, biasb + 512, 16, 64, 512, 576, 768, 2, (const void*)by, 0, 8);  // Wy*cb1+by
    addB(b, CB2, WYB, biasb + 576, 16, 64, 512, 576, 768, 2, (const void*)by, 0, 8);  // Wy*cb2+by
    k_bgemm<<<b.tiles, 256, 0, stream>>>(b); }

  { BBatch b{}; b.n = 0; b.tiles = 0; // asm2 (reads RY1/RY2/CB3 from round 5)
    addB(b, RY2, MAT(SL_AD1T), RY3, 64, 512, 768, 512, 768, 0, nullptr, 0, 8);        // WyA3
    addB(b, RY2, MAT(SL_AD2T), RY4, 64, 512, 768, 512, 768, 0, nullptr, 0, 8);        // WyA4
    addB(b, RY1, FTp(0), RY2 + 512, 64, 64, 768, 512, 768, 0, nullptr, 0, 8);         // WyAF
    addB(b, RY2, FTp(0), RY3 + 512, 64, 64, 768, 512, 768, 0, nullptr, 0, 8);         // WyA2F
    addB(b, CB3, WYB, biasb + 640, 16, 64, 512, 576, 768, 2, (const void*)by, 0, 8);  // Wy*cb3+by
    addB(b, CB4, WYB, biasb + 704, 16, 64, 512, 576, 768, 2, (const void*)by, 0, 8);  // Wy*cb4+by
    k_bgemm<<<b.tiles, 256, 0, stream>>>(b); }

  { BBatch b{}; b.n = 0; b.tiles = 0; // asm3 (reads RY3 / RY*+512 from asm2)
    addB(b, RY3, FTp(0), RY4 + 512, 64, 64, 768, 512, 768, 0, nullptr, 0, 8);         // WyA3F
    addCopy(b, RY1 + 512, 768, RY2 + 576, 64, 64);                                    // WyF+Wyu
    addCopy(b, RY1 + 512, 768, RY3 + 640, 64, 64);
    addCopy(b, RY1 + 512, 768, RY4 + 704, 64, 64);
    addCopy(b, RY2 + 512, 768, RY3 + 576, 64, 64);                                    // WyAF
    addCopy(b, RY2 + 512, 768, RY4 + 640, 64, 64);
    addCopy(b, RY3 + 512, 768, RY4 + 576, 64, 64);                                    // WyA2F
    k_bgemm<<<b.tiles, 256, 0, stream>>>(b); }

  k_phase1t<<<1280, 256, 0, stream>>>(ws + OF_U1CB, ws + OF_FWST, CB8, D8,
                                      ws + OF_ZENC, ws + OF_RWST, CBE16, S8);

  k_add4<<<256, 256, 0, stream>>>(S8, D8s(64));

  { BBatch b{}; b.n = 0; b.tiles = 0; // pairmerge1: d16_m -> S8[2m+1]; E32_i -> D8[68+i]
    for (int m = 0; m < 32; ++m)
      addB(b, D8s(2*m), MAT(SL_AD8W), S8s(2*m+1), 256, 512, 512, 512, 512, 1, D8s(2*m+1), 512, 8);
    for (int i = 0; i < 2; ++i)
      addB(b, D8s(64+2*i), MAT(SL_AE16W), D8s(68+i), 256, 512, 512, 512, 512, 1, D8s(64+2*i+1), 512, 8);
    k_bgemm<<<b.tiles, 256, 0, stream>>>(b); }

  { BBatch b{}; b.n = 0; b.tiles = 0; // pairmerge2: d32_i -> S8[4i+2]; xfin = E32_0*A32e^T + E32_1
    for (int i = 0; i < 16; ++i)
      addB(b, S8s(4*i+1), MAT(SL_AD16W), S8s(4*i+2), 256, 512, 512, 512, 512, 1, S8s(4*i+3), 512, 8);
    addB(b, D8s(68), MAT(SL_QE2W), ws + OF_XFIN, 256, 512, 512, 512, 512, 1, D8s(69), 512, 8);
    k_bgemm<<<b.tiles, 256, 0, stream>>>(b); }

  { BBatch b{}; b.n = 0; b.tiles = 0; // x0hat = xfin * Wx2x^T + bx2x  -> S8[0] directly
    addB(b, ws + OF_XFIN, ws + OF_WX2X, S8s(0), 256, 512, 512, 512, 512, 2, (const void*)bx2x, 0, 8);
    k_bgemm<<<b.tiles, 256, 0, stream>>>(b); }

  { BBatch b{}; b.n = 0; b.tiles = 0; // combine: S32_i -> S8[4i]  (S8[0] already = x0hat)
    addB(b, S8s(0), MAT(SL_QD2W), S8s(4), 256, 512, 512, 512, 512, 1, S8s(2), 512, 8);
    for (int i = 2; i < 16; ++i)
      addB(b, S8s(4*i-6), MAT(SL_QD2W), S8s(4*i), 256, 512, 512, 512, 512, 1, S8s(4*i-2), 512, 8);
    k_bgemm<<<b.tiles, 256, 0, stream>>>(b); }

  { BBatch b{}; b.n = 0; b.tiles = 0; // fill16: S8[4i+2] = S8[4i]*A16^T + d16_{2i}
    for (int i = 0; i < 16; ++i)
      addB(b, S8s(4*i), MAT(SL_AD16W), S8s(4*i+2), 256, 512, 512, 512, 512, 1, S8s(4*i+1), 512, 8);
    k_bgemm<<<b.tiles, 256, 0, stream>>>(b); }

  { BBatch b{}; b.n = 0; b.tiles = 0; // fill8: S8[2j+1] = S8[2j]*A8^T + d8_{2j}; plus yhat0 (T=0)
    for (int j = 0; j < 32; ++j)
      addB(b, S8s(2*j), MAT(SL_AD8W), S8s(2*j+1), 256, 512, 512, 512, 512, 1, D8s(2*j), 512, 8);
    { BItem g{S8s(0), WYB, nullptr, (const void*)by, out, yOff,
              256, 64, 512, 576, 64, 8, 2, b.tiles, 1, 0, 0};
      b.it[b.n++] = g; b.tiles += 4; }
    k_bgemm<<<b.tiles, 256, 0, stream>>>(b); }

  // ---- decode: 2 quad-step launches ----
  short* Xcur = ws + OF_D8;   // D8 region dead after fill8
  k_xstep4<<<1536, 256, 0, stream>>>(S8, Xcur, ws + OF_U1CB, W4, biasb, yOff, out, 0, 0);
  k_xstep4<<<512, 256, 0, stream>>>(Xcur, nullptr, ws + OF_U1CB, W4, biasb, yOff, out, 1, 1);

  (void)in_sizes; (void)n_in; (void)out_size; (void)ws_size;
}